// Round 3
// baseline (1507.816 us; speedup 1.0000x reference)
//
#include <hip/hip_runtime.h>
#include <stdint.h>
#include <math.h>

#define ENC 512
#define NSTEPS 5
// cooperative mega-kernel config
#define NBLK 512
#define NTHR 256
#define NWAVES ((NBLK * NTHR) / 64)       // 2048
// fallback sims config
#define FB_BLOCKS 1024
#define FB_WAVES (FB_BLOCKS * 256 / 64)   // 4096
#define GSTRIDE 100032                    // padded (ncards+1) stride for gumbel table

struct SelState {
  int   taken[8];
  int   takenCount;
  int   active;
  int   outIdx[8];
  float tlp;
};

struct KParams {
  const float *ctx, *cards, *eos, *ctx_w, *ctx_b, *out_w, *out_b;
  const float *w_ih_0, *w_hh_0, *b_ih_0, *b_hh_0;
  const float *w_ih_1, *w_hh_1, *b_ih_1, *b_hh_1;
  unsigned* bar;
  float* xbuf; float* proj;
  float* h0A; float* c0A; float* h1A; float* c1A;
  float* h0B; float* c0B; float* h1B; float* c1B;
  SelState* st;
  float* bScore; int* bIdxA; float* bLogit; float* bM; float* bS;
  float* gtab;
  float* out;
  int ncards;
  uint32_t k0[NSTEPS], k1[NSTEPS];
};

// ---------------- Threefry-2x32-20 (exact JAX implementation) ----------------
__host__ __device__ __forceinline__ void tf2x32(uint32_t k0, uint32_t k1,
                                                uint32_t x0, uint32_t x1,
                                                uint32_t& o0, uint32_t& o1) {
  uint32_t ks0 = k0, ks1 = k1, ks2 = k0 ^ k1 ^ 0x1BD11BDAu;
  uint32_t ks[3] = {ks0, ks1, ks2};
  const uint32_t R0[4] = {13u, 15u, 26u, 6u};
  const uint32_t R1[4] = {17u, 29u, 16u, 24u};
  x0 += ks0; x1 += ks1;
#pragma unroll
  for (int i = 0; i < 5; ++i) {
    const uint32_t* r = (i & 1) ? R1 : R0;
#pragma unroll
    for (int j = 0; j < 4; ++j) {
      x0 += x1;
      x1 = (x1 << r[j]) | (x1 >> (32u - r[j]));
      x1 ^= x0;
    }
    x0 += ks[(i + 1) % 3];
    x1 += ks[(i + 2) % 3] + (uint32_t)(i + 1);
  }
  o0 = x0; o1 = x1;
}

__device__ __forceinline__ float gumbel_from_bits(uint32_t bits) {
  float f = __uint_as_float((bits >> 9) | 0x3F800000u) - 1.0f;   // [0,1)
  float u = (f == 0.0f) ? 1.17549435e-38f : f;                   // minval=FLT_MIN
  return -logf(-logf(u));
}

// ---------------- XLA-matching activations ----------------
__device__ __forceinline__ float xla_tanh(float x) {
  if (fabsf(x) < 0.0004f) return x;
  const float kLim = 7.90531110763549805f;
  float cx = fminf(fmaxf(x, -kLim), kLim);
  float x2 = cx * cx;
  float p = -2.76076847742355e-16f;
  p = fmaf(p, x2, 2.00018790482477e-13f);
  p = fmaf(p, x2, -8.60467152213735e-11f);
  p = fmaf(p, x2, 5.12229709037114e-08f);
  p = fmaf(p, x2, 1.48572235717979e-05f);
  p = fmaf(p, x2, 6.37261928875436e-04f);
  p = fmaf(p, x2, 4.89352455891786e-03f);
  p = cx * p;
  float q = 1.19825839466702e-06f;
  q = fmaf(q, x2, 1.18534705686654e-04f);
  q = fmaf(q, x2, 2.26843463243900e-03f);
  q = fmaf(q, x2, 4.89352518554385e-03f);
  return p / q;
}
__device__ __forceinline__ float xla_sigmoid(float x) {
  return 0.5f * xla_tanh(0.5f * x) + 0.5f;
}

// ---------------- helpers ----------------
__device__ __forceinline__ float dot8(const float4* a, const float4* b, int lane) {
  float4 x0 = a[lane * 2], x1 = a[lane * 2 + 1];
  float4 y0 = b[lane * 2], y1 = b[lane * 2 + 1];
  return x0.x * y0.x + x0.y * y0.y + x0.z * y0.z + x0.w * y0.w +
         x1.x * y1.x + x1.y * y1.y + x1.z * y1.z + x1.w * y1.w;
}
__device__ __forceinline__ float wred(float v) {
#pragma unroll
  for (int k = 1; k < 64; k <<= 1) v += __shfl_xor(v, k, 64);
  return v;
}

// ---- 2-level grid barrier (requires co-residency: cooperative launch) ----
// bar layout (uint): c1[g] at g*16 (64B stride) ; c2 at 1024 ; ep at 1040 ;
//                    gr[g] at 2048+g*32 (128B stride).  64 groups of NBLK/64.
__device__ __forceinline__ void gsync(unsigned* bar, int bid, unsigned target) {
  __syncthreads();
  if (threadIdx.x == 0) {
    const unsigned PERG = NBLK / 64u;
    unsigned g = (unsigned)bid & 63u;
    unsigned* c1 = bar + g * 16u;
    unsigned* c2 = bar + 1024u;
    unsigned* ep = bar + 1040u;
    unsigned* gr = bar + 2048u + g * 32u;
    __threadfence();
    unsigned old = __hip_atomic_fetch_add(c1, 1u, __ATOMIC_ACQ_REL, __HIP_MEMORY_SCOPE_AGENT);
    if ((old & (PERG - 1u)) == (PERG - 1u)) {     // last block of this group
      unsigned o2 = __hip_atomic_fetch_add(c2, 1u, __ATOMIC_ACQ_REL, __HIP_MEMORY_SCOPE_AGENT);
      if ((o2 & 63u) == 63u) {                    // last group overall
        __hip_atomic_fetch_add(ep, 1u, __ATOMIC_RELEASE, __HIP_MEMORY_SCOPE_AGENT);
      }
      while (__hip_atomic_load(ep, __ATOMIC_ACQUIRE, __HIP_MEMORY_SCOPE_AGENT) < target)
        __builtin_amdgcn_s_sleep(2);
      __hip_atomic_store(gr, target, __ATOMIC_RELEASE, __HIP_MEMORY_SCOPE_AGENT);
    } else {
      while (__hip_atomic_load(gr, __ATOMIC_ACQUIRE, __HIP_MEMORY_SCOPE_AGENT) < target)
        __builtin_amdgcn_s_sleep(2);
    }
  }
  __syncthreads();
}

// ---------------- LSTM phase: blocks 0..511, block = output column ----------------
__device__ __forceinline__ void lstm_phase(const float* wih, const float* whh,
                                           const float* bih, const float* bhh,
                                           const float* x, const float* hin, const float* cin,
                                           float* hout, float* cout, float* sG,
                                           int bid, int tid) {
  if (bid < ENC) {
    int g = tid >> 6, lane = tid & 63;
    size_t row = (size_t)(g * ENC + bid) * ENC;
    float accI = dot8((const float4*)(wih + row), (const float4*)x, lane);
    float accH = 0.0f;
    if (hin) accH = dot8((const float4*)(whh + row), (const float4*)hin, lane);
#pragma unroll
    for (int k = 1; k < 64; k <<= 1) {
      accI += __shfl_xor(accI, k, 64);
      accH += __shfl_xor(accH, k, 64);
    }
    if (lane == 0) sG[g] = ((accI + bih[g * ENC + bid]) + accH) + bhh[g * ENC + bid];
    __syncthreads();
    if (tid == 0) {
      float gi = sG[0], gf = sG[1], gg = sG[2], go = sG[3];
      float cprev = cin ? cin[bid] : 0.0f;
      float cn = xla_sigmoid(gf) * cprev + xla_sigmoid(gi) * xla_tanh(gg);
      float hn = xla_sigmoid(go) * xla_tanh(cn);
      cout[bid] = cn;
      hout[bid] = hn;
    }
  }
}

// ---------------- the cooperative mega kernel ----------------
__global__ __launch_bounds__(NTHR, 2) void mega(KParams P) {
  const int bid = blockIdx.x, tid = threadIdx.x;
  const int wid = tid >> 6, lane = tid & 63;
  const int gw = bid * 4 + wid;
  unsigned ph = 0;

  __shared__ float sG[4];
  __shared__ float fS[NTHR], fL[NTHR], fM[NTHR], fU[NTHR];
  __shared__ int   fI[NTHR];
  __shared__ float wSs[4], wLs[4], wMs[4], wUs[4];
  __shared__ int   wIs[4];
  __shared__ int   selSh;

  // ---- phase 0: state init + gumbel table + x0 = ctx @ ctx_w.T + ctx_b ----
  if (bid == 0 && tid == 0) {
    for (int i = 0; i < 8; ++i) { P.st->taken[i] = -1; P.st->outIdx[i] = -1; }
    P.st->takenCount = 0; P.st->active = 1; P.st->tlp = 0.0f;
  }
  {
    int np1 = P.ncards + 1;
    int total = NSTEPS * np1;
    for (int j = bid * NTHR + tid; j < total; j += NBLK * NTHR) {
      int s = j / np1;
      int i = j - s * np1;
      uint32_t r0, r1;
      tf2x32(P.k0[s], P.k1[s], 0u, (uint32_t)i, r0, r1);
      P.gtab[s * GSTRIDE + i] = gumbel_from_bits(r0 ^ r1);
    }
  }
  if (gw >= NWAVES - ENC) {
    int r = gw - (NWAVES - ENC);
    float acc = wred(dot8((const float4*)(P.ctx_w + (size_t)r * ENC), (const float4*)P.ctx, lane));
    if (lane == 0) P.xbuf[r] = acc + P.ctx_b[r];
  }
  gsync(P.bar, bid, ++ph);

  // ---- initial LSTM steps (zero state) ----
  lstm_phase(P.w_ih_0, P.w_hh_0, P.b_ih_0, P.b_hh_0, P.xbuf, nullptr, nullptr,
             P.h0A, P.c0A, sG, bid, tid);
  gsync(P.bar, bid, ++ph);
  lstm_phase(P.w_ih_1, P.w_hh_1, P.b_ih_1, P.b_hh_1, P.h0A, nullptr, nullptr,
             P.h1A, P.c1A, sG, bid, tid);
  gsync(P.bar, bid, ++ph);

  float *h0c = P.h0A, *c0c = P.c0A, *h1c = P.h1A, *c1c = P.c1A;
  float *h0n = P.h0B, *c0n = P.c0B, *h1n = P.h1B, *c1n = P.c1B;

  for (int s = 0; s < NSTEPS; ++s) {
    // ---- A: proj = h1 @ out_w.T + out_b  (waves 0..511) ----
    if (gw < ENC) {
      float acc = wred(dot8((const float4*)(P.out_w + (size_t)gw * ENC), (const float4*)h1c, lane));
      if (lane == 0) P.proj[gw] = acc + P.out_b[gw];
    }
    gsync(P.bar, bid, ++ph);

    // ---- B: sims over all rows, per-block partials ----
    {
      const float4* pv = (const float4*)P.proj;
      float4 p0 = pv[lane * 2], p1 = pv[lane * 2 + 1];
      int t0 = P.st->taken[0], t1 = P.st->taken[1], t2 = P.st->taken[2],
          t3 = P.st->taken[3], t4 = P.st->taken[4];
      const float* gt = P.gtab + s * GSTRIDE;
      float bSc = -INFINITY, bLg = 0.0f, m = -INFINITY, su = 0.0f;
      int bIx = 0x7FFFFFFF;
      for (int i = gw; i <= P.ncards; i += NWAVES) {
        const float* rowp = (i < P.ncards) ? (P.cards + (size_t)i * ENC) : P.eos;
        const float4* er = (const float4*)rowp;
        float4 e0 = er[lane * 2], e1 = er[lane * 2 + 1];
        float acc = p0.x * e0.x + p0.y * e0.y + p0.z * e0.z + p0.w * e0.w +
                    p1.x * e1.x + p1.y * e1.y + p1.z * e1.z + p1.w * e1.w;
        acc = wred(acc);
        bool masked = (i < P.ncards) &&
                      (i == t0 || i == t1 || i == t2 || i == t3 || i == t4);
        if (!masked) {
          if (acc > m) { su = su * expf(m - acc) + 1.0f; m = acc; }
          else         { su += expf(acc - m); }
          float score = gt[i] + acc;
          if (score > bSc || (score == bSc && i < bIx)) { bSc = score; bIx = i; bLg = acc; }
        }
      }
      if (lane == 0) { wSs[wid] = bSc; wIs[wid] = bIx; wLs[wid] = bLg; wMs[wid] = m; wUs[wid] = su; }
      __syncthreads();
      if (tid == 0) {
        float s2 = wSs[0], l2 = wLs[0], m2 = wMs[0], u2 = wUs[0];
        int i2 = wIs[0];
        for (int k = 1; k < 4; ++k) {
          float cs = wSs[k]; int ci = wIs[k];
          if (cs > s2 || (cs == s2 && ci < i2)) { s2 = cs; i2 = ci; l2 = wLs[k]; }
          float cm = wMs[k], cu = wUs[k];
          if (cm > m2) { u2 = u2 * expf(m2 - cm) + cu; m2 = cm; }
          else if (cm > -INFINITY) { u2 += cu * expf(cm - m2); }
        }
        P.bScore[bid] = s2; P.bIdxA[bid] = i2; P.bLogit[bid] = l2; P.bM[bid] = m2; P.bS[bid] = u2;
      }
    }
    gsync(P.bar, bid, ++ph);

    // ---- C: finalize (block 0 only) ----
    if (bid == 0) {
      float bS2 = -INFINITY, bL2 = 0.0f, m = -INFINITY, su = 0.0f;
      int bI2 = 0x7FFFFFFF;
      for (int i = tid; i < NBLK; i += NTHR) {
        float cs = P.bScore[i]; int ci = P.bIdxA[i];
        if (cs > bS2 || (cs == bS2 && ci < bI2)) { bS2 = cs; bI2 = ci; bL2 = P.bLogit[i]; }
        float cm = P.bM[i], cu = P.bS[i];
        if (cm > m) { su = su * expf(m - cm) + cu; m = cm; }
        else if (cm > -INFINITY) { su += cu * expf(cm - m); }
      }
      fS[tid] = bS2; fI[tid] = bI2; fL[tid] = bL2; fM[tid] = m; fU[tid] = su;
      __syncthreads();
      for (int off = 128; off > 0; off >>= 1) {
        if (tid < off) {
          float cs = fS[tid + off]; int ci = fI[tid + off];
          if (cs > fS[tid] || (cs == fS[tid] && ci < fI[tid])) {
            fS[tid] = cs; fI[tid] = ci; fL[tid] = fL[tid + off];
          }
          float cm = fM[tid + off], cu = fU[tid + off];
          if (cm > fM[tid]) { fU[tid] = fU[tid] * expf(fM[tid] - cm) + cu; fM[tid] = cm; }
          else if (cm > -INFINITY) { fU[tid] += cu * expf(cm - fM[tid]); }
        }
        __syncthreads();
      }
      if (tid == 0) {
        int idx = fI[0];
        float lse = fM[0] + logf(fU[0]);
        float lp = fL[0] - lse;
        int active = P.st->active;
        if (active) P.st->tlp += lp;
        int is_eos = (idx == P.ncards);
        int take = active && !is_eos;
        P.st->outIdx[s] = take ? idx : -1;
        if (take) P.st->taken[P.st->takenCount++] = idx;
        P.st->active = active && !is_eos;
        selSh = idx;
        if (s == NSTEPS - 1) {
          for (int q = 0; q < NSTEPS; ++q) P.out[q] = (float)P.st->outIdx[q];
          P.out[NSTEPS] = P.st->tlp;
        }
      }
      __syncthreads();
      if (s < NSTEPS - 1) {
        int idx = selSh;
        const float* row = (idx < P.ncards) ? (P.cards + (size_t)idx * ENC) : P.eos;
        for (int e = tid; e < ENC; e += NTHR) P.xbuf[e] = row[e];
      }
    }
    if (s == NSTEPS - 1) break;   // final LSTM steps are dead code in the reference
    gsync(P.bar, bid, ++ph);

    // ---- D/E: LSTM layers ----
    lstm_phase(P.w_ih_0, P.w_hh_0, P.b_ih_0, P.b_hh_0, P.xbuf, h0c, c0c, h0n, c0n, sG, bid, tid);
    gsync(P.bar, bid, ++ph);
    lstm_phase(P.w_ih_1, P.w_hh_1, P.b_ih_1, P.b_hh_1, h0n, h1c, c1c, h1n, c1n, sG, bid, tid);
    gsync(P.bar, bid, ++ph);

    float* tp;
    tp = h0c; h0c = h0n; h0n = tp;
    tp = c0c; c0c = c0n; c0n = tp;
    tp = h1c; h1c = h1n; h1n = tp;
    tp = c1c; c1c = c1n; c1n = tp;
  }
}

// ================= fallback path (round-1 kernels, + gumbel table) =================
__global__ void init_kernel(float* __restrict__ Z, SelState* st) {
  int t = threadIdx.x;
  if (t < ENC) Z[t] = 0.0f;
  if (t == 0) {
    for (int i = 0; i < 8; ++i) { st->taken[i] = -1; st->outIdx[i] = -1; }
    st->takenCount = 0; st->active = 1; st->tlp = 0.0f;
  }
}

__global__ void gumbel_fill(float* __restrict__ gtab, int ncards,
                            uint32_t k00, uint32_t k01, uint32_t k10, uint32_t k11,
                            uint32_t k20, uint32_t k21, uint32_t k30, uint32_t k31,
                            uint32_t k40, uint32_t k41) {
  uint32_t K0[NSTEPS] = {k00, k10, k20, k30, k40};
  uint32_t K1[NSTEPS] = {k01, k11, k21, k31, k41};
  int np1 = ncards + 1;
  int total = NSTEPS * np1;
  for (int j = blockIdx.x * blockDim.x + threadIdx.x; j < total; j += gridDim.x * blockDim.x) {
    int s = j / np1;
    int i = j - s * np1;
    uint32_t r0, r1;
    tf2x32(K0[s], K1[s], 0u, (uint32_t)i, r0, r1);
    gtab[s * GSTRIDE + i] = gumbel_from_bits(r0 ^ r1);
  }
}

__global__ void matvec512(const float* __restrict__ W, const float* __restrict__ b,
                          const float* __restrict__ vin, float* __restrict__ vout) {
  int tid = blockIdx.x * blockDim.x + threadIdx.x;
  int wave = tid >> 6, lane = tid & 63;
  if (wave >= ENC) return;
  float acc = wred(dot8((const float4*)(W + (size_t)wave * ENC), (const float4*)vin, lane));
  if (lane == 0) vout[wave] = acc + b[wave];
}

__global__ void lstm_step_kernel(const float* __restrict__ w_ih, const float* __restrict__ w_hh,
                                 const float* __restrict__ b_ih, const float* __restrict__ b_hh,
                                 const float* __restrict__ x, const float* __restrict__ h_in,
                                 const float* __restrict__ c_in,
                                 float* __restrict__ h_out, float* __restrict__ c_out) {
  __shared__ float sG[4];
  lstm_phase(w_ih, w_hh, b_ih, b_hh, x, h_in, c_in, h_out, c_out, sG,
             blockIdx.x, threadIdx.x);
}

__global__ void sims_kernel(const float* __restrict__ cards, const float* __restrict__ eos,
                            const float* __restrict__ proj, int ncards,
                            const float* __restrict__ gt,
                            const int* __restrict__ takenList,
                            float* __restrict__ oScore, int* __restrict__ oIdx,
                            float* __restrict__ oLogit, float* __restrict__ oM,
                            float* __restrict__ oS) {
  int tid = blockIdx.x * blockDim.x + threadIdx.x;
  int wave = tid >> 6, lane = tid & 63;
  int nwav = (gridDim.x * blockDim.x) >> 6;
  const float4* pv = (const float4*)proj;
  float4 p0 = pv[lane * 2], p1 = pv[lane * 2 + 1];
  int t0 = takenList[0], t1 = takenList[1], t2 = takenList[2],
      t3 = takenList[3], t4 = takenList[4];
  float bS = -INFINITY, bL = 0.0f, m = -INFINITY, s = 0.0f;
  int bI = 0x7FFFFFFF;
  for (int i = wave; i <= ncards; i += nwav) {
    const float* rowp = (i < ncards) ? (cards + (size_t)i * ENC) : eos;
    const float4* er = (const float4*)rowp;
    float4 e0 = er[lane * 2], e1 = er[lane * 2 + 1];
    float acc = p0.x * e0.x + p0.y * e0.y + p0.z * e0.z + p0.w * e0.w +
                p1.x * e1.x + p1.y * e1.y + p1.z * e1.z + p1.w * e1.w;
    acc = wred(acc);
    bool masked = (i < ncards) &&
                  (i == t0 || i == t1 || i == t2 || i == t3 || i == t4);
    if (!masked) {
      if (acc > m) { s = s * expf(m - acc) + 1.0f; m = acc; }
      else         { s += expf(acc - m); }
      float score = gt[i] + acc;
      if (score > bS || (score == bS && i < bI)) { bS = score; bI = i; bL = acc; }
    }
  }
  if (lane == 0) { oScore[wave] = bS; oIdx[wave] = bI; oLogit[wave] = bL; oM[wave] = m; oS[wave] = s; }
}

__global__ void finalize_kernel(int nw, int step, int ncards,
                                const float* __restrict__ pScore, const int* __restrict__ pIdx,
                                const float* __restrict__ pLogit, const float* __restrict__ pM,
                                const float* __restrict__ pS,
                                const float* __restrict__ cards, const float* __restrict__ eos,
                                SelState* st, float* __restrict__ xout,
                                float* __restrict__ out, int write_out) {
  __shared__ float sS[256], sL[256], sM[256], sU[256];
  __shared__ int sI[256];
  __shared__ int selIdx;
  int t = threadIdx.x;
  float bS = -INFINITY, bL = 0.0f, m = -INFINITY, s = 0.0f;
  int bI = 0x7FFFFFFF;
  for (int i = t; i < nw; i += 256) {
    float cs = pScore[i]; int ci = pIdx[i];
    if (cs > bS || (cs == bS && ci < bI)) { bS = cs; bI = ci; bL = pLogit[i]; }
    float cm = pM[i], cu = pS[i];
    if (cm > m) { s = s * expf(m - cm) + cu; m = cm; }
    else if (cm > -INFINITY) { s += cu * expf(cm - m); }
  }
  sS[t] = bS; sI[t] = bI; sL[t] = bL; sM[t] = m; sU[t] = s;
  __syncthreads();
  for (int off = 128; off > 0; off >>= 1) {
    if (t < off) {
      float cs = sS[t + off]; int ci = sI[t + off];
      if (cs > sS[t] || (cs == sS[t] && ci < sI[t])) { sS[t] = cs; sI[t] = ci; sL[t] = sL[t + off]; }
      float cm = sM[t + off], cu = sU[t + off];
      if (cm > sM[t]) { sU[t] = sU[t] * expf(sM[t] - cm) + cu; sM[t] = cm; }
      else if (cm > -INFINITY) { sU[t] += cu * expf(cm - sM[t]); }
    }
    __syncthreads();
  }
  if (t == 0) {
    int idx = sI[0];
    float lse = sM[0] + logf(sU[0]);
    float lp = sL[0] - lse;
    int active = st->active;
    if (active) st->tlp += lp;
    int is_eos = (idx == ncards);
    int take = active && !is_eos;
    st->outIdx[step] = take ? idx : -1;
    if (take) st->taken[st->takenCount++] = idx;
    st->active = active && !is_eos;
    selIdx = idx;
    if (write_out) {
      for (int q = 0; q < NSTEPS; ++q) out[q] = (float)st->outIdx[q];
      out[NSTEPS] = st->tlp;
    }
  }
  __syncthreads();
  if (!write_out) {
    int idx = selIdx;
    const float* row = (idx < ncards) ? (cards + (size_t)idx * ENC) : eos;
    for (int e = t; e < ENC; e += 256) xout[e] = row[e];
  }
}

// ---------------- host ----------------
extern "C" void kernel_launch(void* const* d_in, const int* in_sizes, int n_in,
                              void* d_out, int out_size, void* d_ws, size_t ws_size,
                              hipStream_t stream) {
  KParams P;
  P.ctx    = (const float*)d_in[0];
  P.cards  = (const float*)d_in[1];
  P.eos    = (const float*)d_in[2];
  P.ctx_w  = (const float*)d_in[3];
  P.ctx_b  = (const float*)d_in[4];
  P.out_w  = (const float*)d_in[5];
  P.out_b  = (const float*)d_in[6];
  P.w_ih_0 = (const float*)d_in[7];
  P.w_hh_0 = (const float*)d_in[8];
  P.b_ih_0 = (const float*)d_in[9];
  P.b_hh_0 = (const float*)d_in[10];
  P.w_ih_1 = (const float*)d_in[11];
  P.w_hh_1 = (const float*)d_in[12];
  P.b_ih_1 = (const float*)d_in[13];
  P.b_hh_1 = (const float*)d_in[14];
  P.ncards = in_sizes[1] / ENC;

  char* wsb = (char*)d_ws;
  P.bar = (unsigned*)wsb;                       // 16 KB barrier region
  float* f = (float*)(wsb + 16384);
  float* Z = f; f += ENC;                       // zeros (fallback)
  P.xbuf = f; f += ENC;
  P.proj = f; f += ENC;
  P.h0A = f; f += ENC;  P.c0A = f; f += ENC;
  P.h1A = f; f += ENC;  P.c1A = f; f += ENC;
  P.h0B = f; f += ENC;  P.c0B = f; f += ENC;
  P.h1B = f; f += ENC;  P.c1B = f; f += ENC;
  P.st = (SelState*)f;  f = (float*)((char*)f + 256);
  P.bScore = f; f += FB_WAVES;                  // sized for fallback (4096); coop uses [0,512)
  P.bIdxA = (int*)f; f += FB_WAVES;
  P.bLogit = f; f += FB_WAVES;
  P.bM = f; f += FB_WAVES;
  P.bS = f; f += FB_WAVES;
  P.gtab = f;
  P.out = (float*)d_out;

  for (int s = 0; s < NSTEPS; ++s)
    tf2x32(0u, 42u, 0u, (uint32_t)s, P.k0[s], P.k1[s]);

  hipMemsetAsync(P.bar, 0, 16384, stream);

  void* args[] = { &P };
  hipError_t ce = hipLaunchCooperativeKernel((void*)mega, dim3(NBLK), dim3(NTHR), args, 0, stream);
  if (ce == hipSuccess) return;
  (void)hipGetLastError();   // clear sticky error; take the classic path

  // ---------------- fallback: round-1 multi-kernel sequence ----------------
  init_kernel<<<1, 512, 0, stream>>>(Z, P.st);
  gumbel_fill<<<512, 256, 0, stream>>>(P.gtab, P.ncards,
                                       P.k0[0], P.k1[0], P.k0[1], P.k1[1], P.k0[2], P.k1[2],
                                       P.k0[3], P.k1[3], P.k0[4], P.k1[4]);
  matvec512<<<128, 256, 0, stream>>>(P.ctx_w, P.ctx_b, P.ctx, P.xbuf);
  lstm_step_kernel<<<512, 256, 0, stream>>>(P.w_ih_0, P.w_hh_0, P.b_ih_0, P.b_hh_0,
                                            P.xbuf, Z, Z, P.h0A, P.c0A);
  lstm_step_kernel<<<512, 256, 0, stream>>>(P.w_ih_1, P.w_hh_1, P.b_ih_1, P.b_hh_1,
                                            P.h0A, Z, Z, P.h1A, P.c1A);
  float *h0c = P.h0A, *c0c = P.c0A, *h1c = P.h1A, *c1c = P.c1A;
  float *h0n = P.h0B, *c0n = P.c0B, *h1n = P.h1B, *c1n = P.c1B;
  for (int s = 0; s < NSTEPS; ++s) {
    matvec512<<<128, 256, 0, stream>>>(P.out_w, P.out_b, h1c, P.proj);
    sims_kernel<<<FB_BLOCKS, 256, 0, stream>>>(P.cards, P.eos, P.proj, P.ncards,
                                               P.gtab + s * GSTRIDE, (const int*)P.st,
                                               P.bScore, P.bIdxA, P.bLogit, P.bM, P.bS);
    finalize_kernel<<<1, 256, 0, stream>>>(FB_WAVES, s, P.ncards,
                                           P.bScore, P.bIdxA, P.bLogit, P.bM, P.bS,
                                           P.cards, P.eos, P.st, P.xbuf,
                                           P.out, (s == NSTEPS - 1) ? 1 : 0);
    if (s == NSTEPS - 1) break;
    lstm_step_kernel<<<512, 256, 0, stream>>>(P.w_ih_0, P.w_hh_0, P.b_ih_0, P.b_hh_0,
                                              P.xbuf, h0c, c0c, h0n, c0n);
    lstm_step_kernel<<<512, 256, 0, stream>>>(P.w_ih_1, P.w_hh_1, P.b_ih_1, P.b_hh_1,
                                              h0n, h1c, c1c, h1n, c1n);
    float* tp;
    tp = h0c; h0c = h0n; h0n = tp;
    tp = c0c; c0c = c0n; c0n = tp;
    tp = h1c; h1c = h1n; h1n = tp;
    tp = c1c; c1c = c1n; c1n = tp;
  }
}

// Round 4
// 617.348 us; speedup vs baseline: 2.4424x; 2.4424x over previous
//
#include <hip/hip_runtime.h>
#include <stdint.h>
#include <math.h>

#define ENC 512
#define NSTEPS 5
// cooperative mega-kernel config
#define NBLK 512
#define NTHR 256
#define NWAVES ((NBLK * NTHR) / 64)       // 2048
// fallback sims config
#define FB_BLOCKS 1024
#define FB_WAVES (FB_BLOCKS * 256 / 64)   // 4096
#define GSTRIDE 100032                    // padded (ncards+1) stride for gumbel table

struct SelState {
  int   taken[8];
  int   takenCount;
  int   active;
  int   outIdx[8];
  float tlp;
};

struct KParams {
  const float *ctx, *cards, *eos, *ctx_w, *ctx_b, *out_w, *out_b;
  const float *w_ih_0, *w_hh_0, *b_ih_0, *b_hh_0;
  const float *w_ih_1, *w_hh_1, *b_ih_1, *b_hh_1;
  unsigned* bar;
  float* xbuf; float* proj;
  float* h0A; float* c0A; float* h1A; float* c1A;
  float* h0B; float* c0B; float* h1B; float* c1B;
  SelState* st;
  float* bScore; int* bIdxA; float* bLogit; float* bM; float* bS;
  float* gtab;
  float* out;
  int ncards;
  uint32_t k0[NSTEPS], k1[NSTEPS];
};

// ---------------- Threefry-2x32-20 (exact JAX implementation) ----------------
__host__ __device__ __forceinline__ void tf2x32(uint32_t k0, uint32_t k1,
                                                uint32_t x0, uint32_t x1,
                                                uint32_t& o0, uint32_t& o1) {
  uint32_t ks0 = k0, ks1 = k1, ks2 = k0 ^ k1 ^ 0x1BD11BDAu;
  uint32_t ks[3] = {ks0, ks1, ks2};
  const uint32_t R0[4] = {13u, 15u, 26u, 6u};
  const uint32_t R1[4] = {17u, 29u, 16u, 24u};
  x0 += ks0; x1 += ks1;
#pragma unroll
  for (int i = 0; i < 5; ++i) {
    const uint32_t* r = (i & 1) ? R1 : R0;
#pragma unroll
    for (int j = 0; j < 4; ++j) {
      x0 += x1;
      x1 = (x1 << r[j]) | (x1 >> (32u - r[j]));
      x1 ^= x0;
    }
    x0 += ks[(i + 1) % 3];
    x1 += ks[(i + 2) % 3] + (uint32_t)(i + 1);
  }
  o0 = x0; o1 = x1;
}

__device__ __forceinline__ float gumbel_from_bits(uint32_t bits) {
  float f = __uint_as_float((bits >> 9) | 0x3F800000u) - 1.0f;   // [0,1)
  float u = (f == 0.0f) ? 1.17549435e-38f : f;                   // minval=FLT_MIN
  return -logf(-logf(u));
}

// ---------------- XLA-matching activations ----------------
__device__ __forceinline__ float xla_tanh(float x) {
  if (fabsf(x) < 0.0004f) return x;
  const float kLim = 7.90531110763549805f;
  float cx = fminf(fmaxf(x, -kLim), kLim);
  float x2 = cx * cx;
  float p = -2.76076847742355e-16f;
  p = fmaf(p, x2, 2.00018790482477e-13f);
  p = fmaf(p, x2, -8.60467152213735e-11f);
  p = fmaf(p, x2, 5.12229709037114e-08f);
  p = fmaf(p, x2, 1.48572235717979e-05f);
  p = fmaf(p, x2, 6.37261928875436e-04f);
  p = fmaf(p, x2, 4.89352455891786e-03f);
  p = cx * p;
  float q = 1.19825839466702e-06f;
  q = fmaf(q, x2, 1.18534705686654e-04f);
  q = fmaf(q, x2, 2.26843463243900e-03f);
  q = fmaf(q, x2, 4.89352518554385e-03f);
  return p / q;
}
__device__ __forceinline__ float xla_sigmoid(float x) {
  return 0.5f * xla_tanh(0.5f * x) + 0.5f;
}

// ---------------- helpers ----------------
__device__ __forceinline__ float dot8(const float4* a, const float4* b, int lane) {
  float4 x0 = a[lane * 2], x1 = a[lane * 2 + 1];
  float4 y0 = b[lane * 2], y1 = b[lane * 2 + 1];
  return x0.x * y0.x + x0.y * y0.y + x0.z * y0.z + x0.w * y0.w +
         x1.x * y1.x + x1.y * y1.y + x1.z * y1.z + x1.w * y1.w;
}
__device__ __forceinline__ float wred(float v) {
#pragma unroll
  for (int k = 1; k < 64; k <<= 1) v += __shfl_xor(v, k, 64);
  return v;
}

// ---- 2-level grid barrier, RELAXED spins (acquire exactly once at exit) ----
// bar layout (uint): c1[g] at g*16 (64B stride) ; c2 at 1024 ; ep at 1040 ;
//                    gr[g] at 2048+g*32 (128B stride).  64 groups of NBLK/64.
__device__ __forceinline__ void gsync(unsigned* bar, int bid, unsigned target) {
  __syncthreads();
  if (threadIdx.x == 0) {
    const unsigned PERG = NBLK / 64u;
    unsigned g = (unsigned)bid & 63u;
    unsigned* c1 = bar + g * 16u;
    unsigned* c2 = bar + 1024u;
    unsigned* ep = bar + 1040u;
    unsigned* gr = bar + 2048u + g * 32u;
    // RELEASE arrival: makes this block's prior writes visible at agent scope.
    unsigned old = __hip_atomic_fetch_add(c1, 1u, __ATOMIC_RELEASE, __HIP_MEMORY_SCOPE_AGENT);
    if ((old & (PERG - 1u)) == (PERG - 1u)) {     // last block of this group
      unsigned o2 = __hip_atomic_fetch_add(c2, 1u, __ATOMIC_RELEASE, __HIP_MEMORY_SCOPE_AGENT);
      if ((o2 & 63u) == 63u) {                    // last group overall
        __hip_atomic_fetch_add(ep, 1u, __ATOMIC_RELEASE, __HIP_MEMORY_SCOPE_AGENT);
      }
      while (__hip_atomic_load(ep, __ATOMIC_RELAXED, __HIP_MEMORY_SCOPE_AGENT) < target)
        __builtin_amdgcn_s_sleep(4);
      __hip_atomic_store(gr, target, __ATOMIC_RELEASE, __HIP_MEMORY_SCOPE_AGENT);
    } else {
      while (__hip_atomic_load(gr, __ATOMIC_RELAXED, __HIP_MEMORY_SCOPE_AGENT) < target)
        __builtin_amdgcn_s_sleep(4);
    }
    // Exactly ONE acquire to invalidate stale cache and see peers' data.
    (void)__hip_atomic_load(ep, __ATOMIC_ACQUIRE, __HIP_MEMORY_SCOPE_AGENT);
  }
  __syncthreads();
}

// ---------------- LSTM phase: blocks 0..511, block = output column ----------------
__device__ __forceinline__ void lstm_phase(const float* wih, const float* whh,
                                           const float* bih, const float* bhh,
                                           const float* x, const float* hin, const float* cin,
                                           float* hout, float* cout, float* sG,
                                           int bid, int tid) {
  if (bid < ENC) {
    int g = tid >> 6, lane = tid & 63;
    size_t row = (size_t)(g * ENC + bid) * ENC;
    float accI = dot8((const float4*)(wih + row), (const float4*)x, lane);
    float accH = 0.0f;
    if (hin) accH = dot8((const float4*)(whh + row), (const float4*)hin, lane);
#pragma unroll
    for (int k = 1; k < 64; k <<= 1) {
      accI += __shfl_xor(accI, k, 64);
      accH += __shfl_xor(accH, k, 64);
    }
    if (lane == 0) sG[g] = ((accI + bih[g * ENC + bid]) + accH) + bhh[g * ENC + bid];
    __syncthreads();
    if (tid == 0) {
      float gi = sG[0], gf = sG[1], gg = sG[2], go = sG[3];
      float cprev = cin ? cin[bid] : 0.0f;
      float cn = xla_sigmoid(gf) * cprev + xla_sigmoid(gi) * xla_tanh(gg);
      float hn = xla_sigmoid(go) * xla_tanh(cn);
      cout[bid] = cn;
      hout[bid] = hn;
    }
  }
}

// ---------------- the cooperative mega kernel ----------------
__global__ __launch_bounds__(NTHR, 2) void mega(KParams P) {
  const int bid = blockIdx.x, tid = threadIdx.x;
  const int wid = tid >> 6, lane = tid & 63;
  const int gw = bid * 4 + wid;
  unsigned ph = 0;

  __shared__ float sG[4];
  __shared__ float fS[NTHR], fL[NTHR], fM[NTHR], fU[NTHR];
  __shared__ int   fI[NTHR];
  __shared__ float wSs[4], wLs[4], wMs[4], wUs[4];
  __shared__ int   wIs[4];
  // per-block replicated selection state (deterministically identical across blocks)
  __shared__ int   sTaken[8];
  __shared__ int   sActive;
  __shared__ float sTlp;
  __shared__ int   sOut[NSTEPS];
  __shared__ int   selSh;

  if (tid == 0) {
    for (int i = 0; i < 8; ++i) sTaken[i] = -1;
    sActive = 1; sTlp = 0.0f;
    for (int i = 0; i < NSTEPS; ++i) sOut[i] = -1;
  }

  // ---- phase 0: gumbel table + x0 = ctx @ ctx_w.T + ctx_b ----
  {
    int np1 = P.ncards + 1;
    int total = NSTEPS * np1;
    for (int j = bid * NTHR + tid; j < total; j += NBLK * NTHR) {
      int s = j / np1;
      int i = j - s * np1;
      uint32_t r0, r1;
      tf2x32(P.k0[s], P.k1[s], 0u, (uint32_t)i, r0, r1);
      P.gtab[s * GSTRIDE + i] = gumbel_from_bits(r0 ^ r1);
    }
  }
  if (gw >= NWAVES - ENC) {
    int r = gw - (NWAVES - ENC);
    float acc = wred(dot8((const float4*)(P.ctx_w + (size_t)r * ENC), (const float4*)P.ctx, lane));
    if (lane == 0) P.xbuf[r] = acc + P.ctx_b[r];
  }
  gsync(P.bar, bid, ++ph);

  // ---- initial LSTM steps (zero state) ----
  lstm_phase(P.w_ih_0, P.w_hh_0, P.b_ih_0, P.b_hh_0, P.xbuf, nullptr, nullptr,
             P.h0A, P.c0A, sG, bid, tid);
  gsync(P.bar, bid, ++ph);
  lstm_phase(P.w_ih_1, P.w_hh_1, P.b_ih_1, P.b_hh_1, P.h0A, nullptr, nullptr,
             P.h1A, P.c1A, sG, bid, tid);
  gsync(P.bar, bid, ++ph);

  float *h0c = P.h0A, *c0c = P.c0A, *h1c = P.h1A, *c1c = P.c1A;
  float *h0n = P.h0B, *c0n = P.c0B, *h1n = P.h1B, *c1n = P.c1B;

  // ---- initial proj ----
  if (gw < ENC) {
    float acc = wred(dot8((const float4*)(P.out_w + (size_t)gw * ENC), (const float4*)h1c, lane));
    if (lane == 0) P.proj[gw] = acc + P.out_b[gw];
  }
  gsync(P.bar, bid, ++ph);

  for (int s = 0; s < NSTEPS; ++s) {
    // ---- B: sims over all rows, per-block partials ----
    {
      const float4* pv = (const float4*)P.proj;
      float4 p0 = pv[lane * 2], p1 = pv[lane * 2 + 1];
      int t0 = sTaken[0], t1 = sTaken[1], t2 = sTaken[2], t3 = sTaken[3], t4 = sTaken[4];
      const float* gt = P.gtab + s * GSTRIDE;
      float bSc = -INFINITY, bLg = 0.0f, m = -INFINITY, su = 0.0f;
      int bIx = 0x7FFFFFFF;
      for (int i = gw; i <= P.ncards; i += NWAVES) {
        const float* rowp = (i < P.ncards) ? (P.cards + (size_t)i * ENC) : P.eos;
        const float4* er = (const float4*)rowp;
        float4 e0 = er[lane * 2], e1 = er[lane * 2 + 1];
        float acc = p0.x * e0.x + p0.y * e0.y + p0.z * e0.z + p0.w * e0.w +
                    p1.x * e1.x + p1.y * e1.y + p1.z * e1.z + p1.w * e1.w;
        acc = wred(acc);
        bool masked = (i < P.ncards) &&
                      (i == t0 || i == t1 || i == t2 || i == t3 || i == t4);
        if (!masked) {
          if (acc > m) { su = su * expf(m - acc) + 1.0f; m = acc; }
          else         { su += expf(acc - m); }
          float score = gt[i] + acc;
          if (score > bSc || (score == bSc && i < bIx)) { bSc = score; bIx = i; bLg = acc; }
        }
      }
      if (lane == 0) { wSs[wid] = bSc; wIs[wid] = bIx; wLs[wid] = bLg; wMs[wid] = m; wUs[wid] = su; }
      __syncthreads();
      if (tid == 0) {
        float s2 = wSs[0], l2 = wLs[0], m2 = wMs[0], u2 = wUs[0];
        int i2 = wIs[0];
        for (int k = 1; k < 4; ++k) {
          float cs = wSs[k]; int ci = wIs[k];
          if (cs > s2 || (cs == s2 && ci < i2)) { s2 = cs; i2 = ci; l2 = wLs[k]; }
          float cm = wMs[k], cu = wUs[k];
          if (cm > m2) { u2 = u2 * expf(m2 - cm) + cu; m2 = cm; }
          else if (cm > -INFINITY) { u2 += cu * expf(cm - m2); }
        }
        P.bScore[bid] = s2; P.bIdxA[bid] = i2; P.bLogit[bid] = l2; P.bM[bid] = m2; P.bS[bid] = u2;
      }
    }
    gsync(P.bar, bid, ++ph);

    // ---- C': every block reduces the 512 partials (identical result) ----
    {
      float bS2 = -INFINITY, bL2 = 0.0f, m = -INFINITY, su = 0.0f;
      int bI2 = 0x7FFFFFFF;
      for (int i = tid; i < NBLK; i += NTHR) {
        float cs = P.bScore[i]; int ci = P.bIdxA[i];
        if (cs > bS2 || (cs == bS2 && ci < bI2)) { bS2 = cs; bI2 = ci; bL2 = P.bLogit[i]; }
        float cm = P.bM[i], cu = P.bS[i];
        if (cm > m) { su = su * expf(m - cm) + cu; m = cm; }
        else if (cm > -INFINITY) { su += cu * expf(cm - m); }
      }
      fS[tid] = bS2; fI[tid] = bI2; fL[tid] = bL2; fM[tid] = m; fU[tid] = su;
      __syncthreads();
      for (int off = 128; off > 0; off >>= 1) {
        if (tid < off) {
          float cs = fS[tid + off]; int ci = fI[tid + off];
          if (cs > fS[tid] || (cs == fS[tid] && ci < fI[tid])) {
            fS[tid] = cs; fI[tid] = ci; fL[tid] = fL[tid + off];
          }
          float cm = fM[tid + off], cu = fU[tid + off];
          if (cm > fM[tid]) { fU[tid] = fU[tid] * expf(fM[tid] - cm) + cu; fM[tid] = cm; }
          else if (cm > -INFINITY) { fU[tid] += cu * expf(cm - fM[tid]); }
        }
        __syncthreads();
      }
      if (tid == 0) {
        int idx = fI[0];
        float lse = fM[0] + logf(fU[0]);
        float lp = fL[0] - lse;
        int active = sActive;
        if (active) sTlp += lp;
        int is_eos = (idx == P.ncards);
        int take = active && !is_eos;
        sOut[s] = take ? idx : -1;
        if (take) {
          for (int q = 0; q < 8; ++q) if (sTaken[q] == -1) { sTaken[q] = idx; break; }
        }
        sActive = active && !is_eos;
        selSh = idx;
        if (s == NSTEPS - 1 && bid == 0) {
          for (int q = 0; q < NSTEPS; ++q) P.out[q] = (float)sOut[q];
          P.out[NSTEPS] = sTlp;
        }
      }
      __syncthreads();
    }
    if (s == NSTEPS - 1) break;   // final LSTM steps are dead code in the reference

    // ---- D: LSTM layer 0, x read directly from the selected row ----
    {
      int idx = selSh;
      const float* xrow = (idx < P.ncards) ? (P.cards + (size_t)idx * ENC) : P.eos;
      lstm_phase(P.w_ih_0, P.w_hh_0, P.b_ih_0, P.b_hh_0, xrow, h0c, c0c, h0n, c0n, sG, bid, tid);
    }
    gsync(P.bar, bid, ++ph);
    // ---- E: LSTM layer 1 ----
    lstm_phase(P.w_ih_1, P.w_hh_1, P.b_ih_1, P.b_hh_1, h0n, h1c, c1c, h1n, c1n, sG, bid, tid);
    gsync(P.bar, bid, ++ph);

    float* tp;
    tp = h0c; h0c = h0n; h0n = tp;
    tp = c0c; c0c = c0n; c0n = tp;
    tp = h1c; h1c = h1n; h1n = tp;
    tp = c1c; c1c = c1n; c1n = tp;

    // ---- A: proj for next step ----
    if (gw < ENC) {
      float acc = wred(dot8((const float4*)(P.out_w + (size_t)gw * ENC), (const float4*)h1c, lane));
      if (lane == 0) P.proj[gw] = acc + P.out_b[gw];
    }
    gsync(P.bar, bid, ++ph);
  }
}

// ================= fallback path (round-1 kernels, + gumbel table) =================
__global__ void init_kernel(float* __restrict__ Z, SelState* st) {
  int t = threadIdx.x;
  if (t < ENC) Z[t] = 0.0f;
  if (t == 0) {
    for (int i = 0; i < 8; ++i) { st->taken[i] = -1; st->outIdx[i] = -1; }
    st->takenCount = 0; st->active = 1; st->tlp = 0.0f;
  }
}

__global__ void gumbel_fill(float* __restrict__ gtab, int ncards,
                            uint32_t k00, uint32_t k01, uint32_t k10, uint32_t k11,
                            uint32_t k20, uint32_t k21, uint32_t k30, uint32_t k31,
                            uint32_t k40, uint32_t k41) {
  uint32_t K0[NSTEPS] = {k00, k10, k20, k30, k40};
  uint32_t K1[NSTEPS] = {k01, k11, k21, k31, k41};
  int np1 = ncards + 1;
  int total = NSTEPS * np1;
  for (int j = blockIdx.x * blockDim.x + threadIdx.x; j < total; j += gridDim.x * blockDim.x) {
    int s = j / np1;
    int i = j - s * np1;
    uint32_t r0, r1;
    tf2x32(K0[s], K1[s], 0u, (uint32_t)i, r0, r1);
    gtab[s * GSTRIDE + i] = gumbel_from_bits(r0 ^ r1);
  }
}

__global__ void matvec512(const float* __restrict__ W, const float* __restrict__ b,
                          const float* __restrict__ vin, float* __restrict__ vout) {
  int tid = blockIdx.x * blockDim.x + threadIdx.x;
  int wave = tid >> 6, lane = tid & 63;
  if (wave >= ENC) return;
  float acc = wred(dot8((const float4*)(W + (size_t)wave * ENC), (const float4*)vin, lane));
  if (lane == 0) vout[wave] = acc + b[wave];
}

__global__ void lstm_step_kernel(const float* __restrict__ w_ih, const float* __restrict__ w_hh,
                                 const float* __restrict__ b_ih, const float* __restrict__ b_hh,
                                 const float* __restrict__ x, const float* __restrict__ h_in,
                                 const float* __restrict__ c_in,
                                 float* __restrict__ h_out, float* __restrict__ c_out) {
  __shared__ float sG[4];
  lstm_phase(w_ih, w_hh, b_ih, b_hh, x, h_in, c_in, h_out, c_out, sG,
             blockIdx.x, threadIdx.x);
}

__global__ void sims_kernel(const float* __restrict__ cards, const float* __restrict__ eos,
                            const float* __restrict__ proj, int ncards,
                            const float* __restrict__ gt,
                            const int* __restrict__ takenList,
                            float* __restrict__ oScore, int* __restrict__ oIdx,
                            float* __restrict__ oLogit, float* __restrict__ oM,
                            float* __restrict__ oS) {
  int tid = blockIdx.x * blockDim.x + threadIdx.x;
  int wave = tid >> 6, lane = tid & 63;
  int nwav = (gridDim.x * blockDim.x) >> 6;
  const float4* pv = (const float4*)proj;
  float4 p0 = pv[lane * 2], p1 = pv[lane * 2 + 1];
  int t0 = takenList[0], t1 = takenList[1], t2 = takenList[2],
      t3 = takenList[3], t4 = takenList[4];
  float bS = -INFINITY, bL = 0.0f, m = -INFINITY, s = 0.0f;
  int bI = 0x7FFFFFFF;
  for (int i = wave; i <= ncards; i += nwav) {
    const float* rowp = (i < ncards) ? (cards + (size_t)i * ENC) : eos;
    const float4* er = (const float4*)rowp;
    float4 e0 = er[lane * 2], e1 = er[lane * 2 + 1];
    float acc = p0.x * e0.x + p0.y * e0.y + p0.z * e0.z + p0.w * e0.w +
                p1.x * e1.x + p1.y * e1.y + p1.z * e1.z + p1.w * e1.w;
    acc = wred(acc);
    bool masked = (i < ncards) &&
                  (i == t0 || i == t1 || i == t2 || i == t3 || i == t4);
    if (!masked) {
      if (acc > m) { s = s * expf(m - acc) + 1.0f; m = acc; }
      else         { s += expf(acc - m); }
      float score = gt[i] + acc;
      if (score > bS || (score == bS && i < bI)) { bS = score; bI = i; bL = acc; }
    }
  }
  if (lane == 0) { oScore[wave] = bS; oIdx[wave] = bI; oLogit[wave] = bL; oM[wave] = m; oS[wave] = s; }
}

__global__ void finalize_kernel(int nw, int step, int ncards,
                                const float* __restrict__ pScore, const int* __restrict__ pIdx,
                                const float* __restrict__ pLogit, const float* __restrict__ pM,
                                const float* __restrict__ pS,
                                const float* __restrict__ cards, const float* __restrict__ eos,
                                SelState* st, float* __restrict__ xout,
                                float* __restrict__ out, int write_out) {
  __shared__ float sS[256], sL[256], sM[256], sU[256];
  __shared__ int sI[256];
  __shared__ int selIdx;
  int t = threadIdx.x;
  float bS = -INFINITY, bL = 0.0f, m = -INFINITY, s = 0.0f;
  int bI = 0x7FFFFFFF;
  for (int i = t; i < nw; i += 256) {
    float cs = pScore[i]; int ci = pIdx[i];
    if (cs > bS || (cs == bS && ci < bI)) { bS = cs; bI = ci; bL = pLogit[i]; }
    float cm = pM[i], cu = pS[i];
    if (cm > m) { s = s * expf(m - cm) + cu; m = cm; }
    else if (cm > -INFINITY) { s += cu * expf(cm - m); }
  }
  sS[t] = bS; sI[t] = bI; sL[t] = bL; sM[t] = m; sU[t] = s;
  __syncthreads();
  for (int off = 128; off > 0; off >>= 1) {
    if (t < off) {
      float cs = sS[t + off]; int ci = sI[t + off];
      if (cs > sS[t] || (cs == sS[t] && ci < sI[t])) { sS[t] = cs; sI[t] = ci; sL[t] = sL[t + off]; }
      float cm = sM[t + off], cu = sU[t + off];
      if (cm > sM[t]) { sU[t] = sU[t] * expf(sM[t] - cm) + cu; sM[t] = cm; }
      else if (cm > -INFINITY) { sU[t] += cu * expf(cm - sM[t]); }
    }
    __syncthreads();
  }
  if (t == 0) {
    int idx = sI[0];
    float lse = sM[0] + logf(sU[0]);
    float lp = sL[0] - lse;
    int active = st->active;
    if (active) st->tlp += lp;
    int is_eos = (idx == ncards);
    int take = active && !is_eos;
    st->outIdx[step] = take ? idx : -1;
    if (take) st->taken[st->takenCount++] = idx;
    st->active = active && !is_eos;
    selIdx = idx;
    if (write_out) {
      for (int q = 0; q < NSTEPS; ++q) out[q] = (float)st->outIdx[q];
      out[NSTEPS] = st->tlp;
    }
  }
  __syncthreads();
  if (!write_out) {
    int idx = selIdx;
    const float* row = (idx < ncards) ? (cards + (size_t)idx * ENC) : eos;
    for (int e = t; e < ENC; e += 256) xout[e] = row[e];
  }
}

// ---------------- host ----------------
extern "C" void kernel_launch(void* const* d_in, const int* in_sizes, int n_in,
                              void* d_out, int out_size, void* d_ws, size_t ws_size,
                              hipStream_t stream) {
  KParams P;
  P.ctx    = (const float*)d_in[0];
  P.cards  = (const float*)d_in[1];
  P.eos    = (const float*)d_in[2];
  P.ctx_w  = (const float*)d_in[3];
  P.ctx_b  = (const float*)d_in[4];
  P.out_w  = (const float*)d_in[5];
  P.out_b  = (const float*)d_in[6];
  P.w_ih_0 = (const float*)d_in[7];
  P.w_hh_0 = (const float*)d_in[8];
  P.b_ih_0 = (const float*)d_in[9];
  P.b_hh_0 = (const float*)d_in[10];
  P.w_ih_1 = (const float*)d_in[11];
  P.w_hh_1 = (const float*)d_in[12];
  P.b_ih_1 = (const float*)d_in[13];
  P.b_hh_1 = (const float*)d_in[14];
  P.ncards = in_sizes[1] / ENC;

  char* wsb = (char*)d_ws;
  P.bar = (unsigned*)wsb;                       // 16 KB barrier region
  float* f = (float*)(wsb + 16384);
  float* Z = f; f += ENC;                       // zeros (fallback)
  P.xbuf = f; f += ENC;
  P.proj = f; f += ENC;
  P.h0A = f; f += ENC;  P.c0A = f; f += ENC;
  P.h1A = f; f += ENC;  P.c1A = f; f += ENC;
  P.h0B = f; f += ENC;  P.c0B = f; f += ENC;
  P.h1B = f; f += ENC;  P.c1B = f; f += ENC;
  P.st = (SelState*)f;  f = (float*)((char*)f + 256);
  P.bScore = f; f += FB_WAVES;                  // sized for fallback (4096); coop uses [0,512)
  P.bIdxA = (int*)f; f += FB_WAVES;
  P.bLogit = f; f += FB_WAVES;
  P.bM = f; f += FB_WAVES;
  P.bS = f; f += FB_WAVES;
  P.gtab = f;
  P.out = (float*)d_out;

  for (int s = 0; s < NSTEPS; ++s)
    tf2x32(0u, 42u, 0u, (uint32_t)s, P.k0[s], P.k1[s]);

  hipMemsetAsync(P.bar, 0, 16384, stream);

  void* args[] = { &P };
  hipError_t ce = hipLaunchCooperativeKernel((void*)mega, dim3(NBLK), dim3(NTHR), args, 0, stream);
  if (ce == hipSuccess) return;
  (void)hipGetLastError();   // clear sticky error; take the classic path

  // ---------------- fallback: round-1 multi-kernel sequence ----------------
  init_kernel<<<1, 512, 0, stream>>>(Z, P.st);
  gumbel_fill<<<512, 256, 0, stream>>>(P.gtab, P.ncards,
                                       P.k0[0], P.k1[0], P.k0[1], P.k1[1], P.k0[2], P.k1[2],
                                       P.k0[3], P.k1[3], P.k0[4], P.k1[4]);
  matvec512<<<128, 256, 0, stream>>>(P.ctx_w, P.ctx_b, P.ctx, P.xbuf);
  lstm_step_kernel<<<512, 256, 0, stream>>>(P.w_ih_0, P.w_hh_0, P.b_ih_0, P.b_hh_0,
                                            P.xbuf, Z, Z, P.h0A, P.c0A);
  lstm_step_kernel<<<512, 256, 0, stream>>>(P.w_ih_1, P.w_hh_1, P.b_ih_1, P.b_hh_1,
                                            P.h0A, Z, Z, P.h1A, P.c1A);
  float *h0c = P.h0A, *c0c = P.c0A, *h1c = P.h1A, *c1c = P.c1A;
  float *h0n = P.h0B, *c0n = P.c0B, *h1n = P.h1B, *c1n = P.c1B;
  for (int s = 0; s < NSTEPS; ++s) {
    matvec512<<<128, 256, 0, stream>>>(P.out_w, P.out_b, h1c, P.proj);
    sims_kernel<<<FB_BLOCKS, 256, 0, stream>>>(P.cards, P.eos, P.proj, P.ncards,
                                               P.gtab + s * GSTRIDE, (const int*)P.st,
                                               P.bScore, P.bIdxA, P.bLogit, P.bM, P.bS);
    finalize_kernel<<<1, 256, 0, stream>>>(FB_WAVES, s, P.ncards,
                                           P.bScore, P.bIdxA, P.bLogit, P.bM, P.bS,
                                           P.cards, P.eos, P.st, P.xbuf,
                                           P.out, (s == NSTEPS - 1) ? 1 : 0);
    if (s == NSTEPS - 1) break;
    lstm_step_kernel<<<512, 256, 0, stream>>>(P.w_ih_0, P.w_hh_0, P.b_ih_0, P.b_hh_0,
                                              P.xbuf, h0c, c0c, h0n, c0n);
    lstm_step_kernel<<<512, 256, 0, stream>>>(P.w_ih_1, P.w_hh_1, P.b_ih_1, P.b_hh_1,
                                              h0n, h1c, c1c, h1n, c1n);
    float* tp;
    tp = h0c; h0c = h0n; h0n = tp;
    tp = c0c; c0c = c0n; c0n = tp;
    tp = h1c; h1c = h1n; h1n = tp;
    tp = c1c; c1c = c1n; c1n = tp;
  }
}

// Round 5
// 530.064 us; speedup vs baseline: 2.8446x; 1.1647x over previous
//
#include <hip/hip_runtime.h>
#include <stdint.h>
#include <math.h>

#define ENC 512
#define NSTEPS 5
// cooperative mega-kernel config
#define NBLK 512
#define NTHR 256
#define NWAVES ((NBLK * NTHR) / 64)       // 2048
// fallback sims config
#define FB_BLOCKS 1024
#define FB_WAVES (FB_BLOCKS * 256 / 64)   // 4096
#define GSTRIDE 100032                    // padded (ncards+1) stride for gumbel table

struct SelState {
  int   taken[8];
  int   takenCount;
  int   active;
  int   outIdx[8];
  float tlp;
};

struct KParams {
  const float *ctx, *cards, *eos, *ctx_w, *ctx_b, *out_w, *out_b;
  const float *w_ih_0, *w_hh_0, *b_ih_0, *b_hh_0;
  const float *w_ih_1, *w_hh_1, *b_ih_1, *b_hh_1;
  unsigned* bar;
  float* xbuf; float* proj;
  float* h0A; float* c0A; float* h1A; float* c1A;
  float* h0B; float* c0B; float* h1B; float* c1B;
  SelState* st;
  float* bScore; int* bIdxA; float* bLogit; float* bM; float* bS;
  float* gtab;
  float* out;
  int ncards;
  uint32_t k0[NSTEPS], k1[NSTEPS];
};

// ---------------- Threefry-2x32-20 (exact JAX implementation) ----------------
__host__ __device__ __forceinline__ void tf2x32(uint32_t k0, uint32_t k1,
                                                uint32_t x0, uint32_t x1,
                                                uint32_t& o0, uint32_t& o1) {
  uint32_t ks0 = k0, ks1 = k1, ks2 = k0 ^ k1 ^ 0x1BD11BDAu;
  uint32_t ks[3] = {ks0, ks1, ks2};
  const uint32_t R0[4] = {13u, 15u, 26u, 6u};
  const uint32_t R1[4] = {17u, 29u, 16u, 24u};
  x0 += ks0; x1 += ks1;
#pragma unroll
  for (int i = 0; i < 5; ++i) {
    const uint32_t* r = (i & 1) ? R1 : R0;
#pragma unroll
    for (int j = 0; j < 4; ++j) {
      x0 += x1;
      x1 = (x1 << r[j]) | (x1 >> (32u - r[j]));
      x1 ^= x0;
    }
    x0 += ks[(i + 1) % 3];
    x1 += ks[(i + 2) % 3] + (uint32_t)(i + 1);
  }
  o0 = x0; o1 = x1;
}

__device__ __forceinline__ float gumbel_from_bits(uint32_t bits) {
  float f = __uint_as_float((bits >> 9) | 0x3F800000u) - 1.0f;   // [0,1)
  float u = (f == 0.0f) ? 1.17549435e-38f : f;                   // minval=FLT_MIN
  return -logf(-logf(u));
}

// ---------------- XLA-matching activations ----------------
__device__ __forceinline__ float xla_tanh(float x) {
  if (fabsf(x) < 0.0004f) return x;
  const float kLim = 7.90531110763549805f;
  float cx = fminf(fmaxf(x, -kLim), kLim);
  float x2 = cx * cx;
  float p = -2.76076847742355e-16f;
  p = fmaf(p, x2, 2.00018790482477e-13f);
  p = fmaf(p, x2, -8.60467152213735e-11f);
  p = fmaf(p, x2, 5.12229709037114e-08f);
  p = fmaf(p, x2, 1.48572235717979e-05f);
  p = fmaf(p, x2, 6.37261928875436e-04f);
  p = fmaf(p, x2, 4.89352455891786e-03f);
  p = cx * p;
  float q = 1.19825839466702e-06f;
  q = fmaf(q, x2, 1.18534705686654e-04f);
  q = fmaf(q, x2, 2.26843463243900e-03f);
  q = fmaf(q, x2, 4.89352518554385e-03f);
  return p / q;
}
__device__ __forceinline__ float xla_sigmoid(float x) {
  return 0.5f * xla_tanh(0.5f * x) + 0.5f;
}

// ---------------- helpers ----------------
__device__ __forceinline__ float dot8(const float4* a, const float4* b, int lane) {
  float4 x0 = a[lane * 2], x1 = a[lane * 2 + 1];
  float4 y0 = b[lane * 2], y1 = b[lane * 2 + 1];
  return x0.x * y0.x + x0.y * y0.y + x0.z * y0.z + x0.w * y0.w +
         x1.x * y1.x + x1.y * y1.y + x1.z * y1.z + x1.w * y1.w;
}
__device__ __forceinline__ float wred(float v) {
#pragma unroll
  for (int k = 1; k < 64; k <<= 1) v += __shfl_xor(v, k, 64);
  return v;
}

// ---- zero-RMW grid barrier ----
// slots[b] at bar + b*16 (64B stride, 512 slots = 32 KB)
// rel[g]   at bar + 8192 + g*16 (64 replicas, 4 KB)
// Arrival: per-block private release-store (no contention, fully parallel).
// Block 0: 256 threads poll 2 slots each; one acquire; one wave writes 64
// release replicas with a single lane-parallel store. Followers poll replica.
__device__ __forceinline__ void gsync(unsigned* bar, int bid, unsigned target) {
  __syncthreads();
  const int tid = threadIdx.x;
  unsigned* slots = bar;
  unsigned* rel   = bar + 8192;
  if (tid == 0)
    __hip_atomic_store(&slots[(unsigned)bid * 16u], target,
                       __ATOMIC_RELEASE, __HIP_MEMORY_SCOPE_AGENT);
  if (bid == 0) {
    unsigned* s0 = &slots[(2u * (unsigned)tid) * 16u];
    unsigned* s1 = &slots[(2u * (unsigned)tid + 1u) * 16u];
    while (__hip_atomic_load(s0, __ATOMIC_RELAXED, __HIP_MEMORY_SCOPE_AGENT) < target)
      __builtin_amdgcn_s_sleep(1);
    while (__hip_atomic_load(s1, __ATOMIC_RELAXED, __HIP_MEMORY_SCOPE_AGENT) < target)
      __builtin_amdgcn_s_sleep(1);
    __syncthreads();                     // all 512 slots observed
    if (tid == 0)
      (void)__hip_atomic_load(&slots[0], __ATOMIC_ACQUIRE, __HIP_MEMORY_SCOPE_AGENT);
    __syncthreads();                     // acquire ordered before release replicas
    if (tid < 64)
      __hip_atomic_store(&rel[(unsigned)tid * 16u], target,
                         __ATOMIC_RELEASE, __HIP_MEMORY_SCOPE_AGENT);
  } else {
    if (tid == 0) {
      unsigned* r = &rel[((unsigned)bid & 63u) * 16u];
      while (__hip_atomic_load(r, __ATOMIC_RELAXED, __HIP_MEMORY_SCOPE_AGENT) < target)
        __builtin_amdgcn_s_sleep(1);
      (void)__hip_atomic_load(r, __ATOMIC_ACQUIRE, __HIP_MEMORY_SCOPE_AGENT);
    }
    __syncthreads();
  }
}

// ---------------- LSTM phase: blocks 0..511, block = output column ----------------
__device__ __forceinline__ void lstm_phase(const float* wih, const float* whh,
                                           const float* bih, const float* bhh,
                                           const float* x, const float* hin, const float* cin,
                                           float* hout, float* cout, float* sG,
                                           int bid, int tid) {
  if (bid < ENC) {
    int g = tid >> 6, lane = tid & 63;
    size_t row = (size_t)(g * ENC + bid) * ENC;
    float accI = dot8((const float4*)(wih + row), (const float4*)x, lane);
    float accH = 0.0f;
    if (hin) accH = dot8((const float4*)(whh + row), (const float4*)hin, lane);
#pragma unroll
    for (int k = 1; k < 64; k <<= 1) {
      accI += __shfl_xor(accI, k, 64);
      accH += __shfl_xor(accH, k, 64);
    }
    if (lane == 0) sG[g] = ((accI + bih[g * ENC + bid]) + accH) + bhh[g * ENC + bid];
    __syncthreads();
    if (tid == 0) {
      float gi = sG[0], gf = sG[1], gg = sG[2], go = sG[3];
      float cprev = cin ? cin[bid] : 0.0f;
      float cn = xla_sigmoid(gf) * cprev + xla_sigmoid(gi) * xla_tanh(gg);
      float hn = xla_sigmoid(go) * xla_tanh(cn);
      cout[bid] = cn;
      hout[bid] = hn;
    }
  }
}

// ---------------- the cooperative mega kernel ----------------
__global__ __launch_bounds__(NTHR, 2) void mega(KParams P) {
  const int bid = blockIdx.x, tid = threadIdx.x;
  const int wid = tid >> 6, lane = tid & 63;
  const int gw = bid * 4 + wid;
  unsigned ph = 0;

  __shared__ float sG[4];
  __shared__ float fS[NTHR], fL[NTHR], fM[NTHR], fU[NTHR];
  __shared__ int   fI[NTHR];
  __shared__ float wSs[4], wLs[4], wMs[4], wUs[4];
  __shared__ int   wIs[4];
  // per-block replicated selection state (deterministically identical everywhere)
  __shared__ int   sTaken[8];
  __shared__ int   sActive;
  __shared__ float sTlp;
  __shared__ int   sOut[NSTEPS];
  __shared__ int   selSh;

  if (tid == 0) {
    for (int i = 0; i < 8; ++i) sTaken[i] = -1;
    sActive = 1; sTlp = 0.0f;
    for (int i = 0; i < NSTEPS; ++i) sOut[i] = -1;
  }

  // ---- phase 0: gumbel table + x0 = ctx @ ctx_w.T + ctx_b ----
  {
    int np1 = P.ncards + 1;
    int total = NSTEPS * np1;
    for (int j = bid * NTHR + tid; j < total; j += NBLK * NTHR) {
      int s = j / np1;
      int i = j - s * np1;
      uint32_t r0, r1;
      tf2x32(P.k0[s], P.k1[s], 0u, (uint32_t)i, r0, r1);
      P.gtab[s * GSTRIDE + i] = gumbel_from_bits(r0 ^ r1);
    }
  }
  if (gw >= NWAVES - ENC) {
    int r = gw - (NWAVES - ENC);
    float acc = wred(dot8((const float4*)(P.ctx_w + (size_t)r * ENC), (const float4*)P.ctx, lane));
    if (lane == 0) P.xbuf[r] = acc + P.ctx_b[r];
  }
  gsync(P.bar, bid, ++ph);

  // ---- initial LSTM steps (zero state) ----
  lstm_phase(P.w_ih_0, P.w_hh_0, P.b_ih_0, P.b_hh_0, P.xbuf, nullptr, nullptr,
             P.h0A, P.c0A, sG, bid, tid);
  gsync(P.bar, bid, ++ph);
  lstm_phase(P.w_ih_1, P.w_hh_1, P.b_ih_1, P.b_hh_1, P.h0A, nullptr, nullptr,
             P.h1A, P.c1A, sG, bid, tid);
  gsync(P.bar, bid, ++ph);

  float *h0c = P.h0A, *c0c = P.c0A, *h1c = P.h1A, *c1c = P.c1A;
  float *h0n = P.h0B, *c0n = P.c0B, *h1n = P.h1B, *c1n = P.c1B;

  // ---- initial proj ----
  if (gw < ENC) {
    float acc = wred(dot8((const float4*)(P.out_w + (size_t)gw * ENC), (const float4*)h1c, lane));
    if (lane == 0) P.proj[gw] = acc + P.out_b[gw];
  }
  gsync(P.bar, bid, ++ph);

  for (int s = 0; s < NSTEPS; ++s) {
    // ---- B: sims over all rows (2-row software pipeline), per-block partials ----
    {
      const float4* pv = (const float4*)P.proj;
      float4 p0 = pv[lane * 2], p1 = pv[lane * 2 + 1];
      int t0 = sTaken[0], t1 = sTaken[1], t2 = sTaken[2], t3 = sTaken[3], t4 = sTaken[4];
      const float* gt = P.gtab + s * GSTRIDE;
      float bSc = -INFINITY, bLg = 0.0f, m = -INFINITY, su = 0.0f;
      int bIx = 0x7FFFFFFF;
      for (int i = gw; i <= P.ncards; i += 2 * NWAVES) {
        int i2 = i + NWAVES;
        bool has2 = (i2 <= P.ncards);
        const float* rp1 = (i < P.ncards) ? (P.cards + (size_t)i * ENC) : P.eos;
        const float* rp2 = has2 ? ((i2 < P.ncards) ? (P.cards + (size_t)i2 * ENC) : P.eos) : rp1;
        const float4* er1 = (const float4*)rp1;
        const float4* er2 = (const float4*)rp2;
        float4 a0 = er1[lane * 2], a1 = er1[lane * 2 + 1];
        float4 b0 = er2[lane * 2], b1 = er2[lane * 2 + 1];
        float acc1 = p0.x * a0.x + p0.y * a0.y + p0.z * a0.z + p0.w * a0.w +
                     p1.x * a1.x + p1.y * a1.y + p1.z * a1.z + p1.w * a1.w;
        float acc2 = p0.x * b0.x + p0.y * b0.y + p0.z * b0.z + p0.w * b0.w +
                     p1.x * b1.x + p1.y * b1.y + p1.z * b1.z + p1.w * b1.w;
#pragma unroll
        for (int k = 1; k < 64; k <<= 1) {
          acc1 += __shfl_xor(acc1, k, 64);
          acc2 += __shfl_xor(acc2, k, 64);
        }
        {
          bool masked = (i < P.ncards) &&
                        (i == t0 || i == t1 || i == t2 || i == t3 || i == t4);
          if (!masked) {
            if (acc1 > m) { su = su * expf(m - acc1) + 1.0f; m = acc1; }
            else          { su += expf(acc1 - m); }
            float score = gt[i] + acc1;
            if (score > bSc || (score == bSc && i < bIx)) { bSc = score; bIx = i; bLg = acc1; }
          }
        }
        if (has2) {
          bool masked = (i2 < P.ncards) &&
                        (i2 == t0 || i2 == t1 || i2 == t2 || i2 == t3 || i2 == t4);
          if (!masked) {
            if (acc2 > m) { su = su * expf(m - acc2) + 1.0f; m = acc2; }
            else          { su += expf(acc2 - m); }
            float score = gt[i2] + acc2;
            if (score > bSc || (score == bSc && i2 < bIx)) { bSc = score; bIx = i2; bLg = acc2; }
          }
        }
      }
      if (lane == 0) { wSs[wid] = bSc; wIs[wid] = bIx; wLs[wid] = bLg; wMs[wid] = m; wUs[wid] = su; }
      __syncthreads();
      if (tid == 0) {
        float s2 = wSs[0], l2 = wLs[0], m2 = wMs[0], u2 = wUs[0];
        int i2 = wIs[0];
        for (int k = 1; k < 4; ++k) {
          float cs = wSs[k]; int ci = wIs[k];
          if (cs > s2 || (cs == s2 && ci < i2)) { s2 = cs; i2 = ci; l2 = wLs[k]; }
          float cm = wMs[k], cu = wUs[k];
          if (cm > m2) { u2 = u2 * expf(m2 - cm) + cu; m2 = cm; }
          else if (cm > -INFINITY) { u2 += cu * expf(cm - m2); }
        }
        P.bScore[bid] = s2; P.bIdxA[bid] = i2; P.bLogit[bid] = l2; P.bM[bid] = m2; P.bS[bid] = u2;
      }
    }
    gsync(P.bar, bid, ++ph);

    // ---- C': every block reduces the 512 partials (identical result) ----
    {
      float bS2 = -INFINITY, bL2 = 0.0f, m = -INFINITY, su = 0.0f;
      int bI2 = 0x7FFFFFFF;
      for (int i = tid; i < NBLK; i += NTHR) {
        float cs = P.bScore[i]; int ci = P.bIdxA[i];
        if (cs > bS2 || (cs == bS2 && ci < bI2)) { bS2 = cs; bI2 = ci; bL2 = P.bLogit[i]; }
        float cm = P.bM[i], cu = P.bS[i];
        if (cm > m) { su = su * expf(m - cm) + cu; m = cm; }
        else if (cm > -INFINITY) { su += cu * expf(cm - m); }
      }
      fS[tid] = bS2; fI[tid] = bI2; fL[tid] = bL2; fM[tid] = m; fU[tid] = su;
      __syncthreads();
      for (int off = 128; off > 0; off >>= 1) {
        if (tid < off) {
          float cs = fS[tid + off]; int ci = fI[tid + off];
          if (cs > fS[tid] || (cs == fS[tid] && ci < fI[tid])) {
            fS[tid] = cs; fI[tid] = ci; fL[tid] = fL[tid + off];
          }
          float cm = fM[tid + off], cu = fU[tid + off];
          if (cm > fM[tid]) { fU[tid] = fU[tid] * expf(fM[tid] - cm) + cu; fM[tid] = cm; }
          else if (cm > -INFINITY) { fU[tid] += cu * expf(cm - fM[tid]); }
        }
        __syncthreads();
      }
      if (tid == 0) {
        int idx = fI[0];
        float lse = fM[0] + logf(fU[0]);
        float lp = fL[0] - lse;
        int active = sActive;
        if (active) sTlp += lp;
        int is_eos = (idx == P.ncards);
        int take = active && !is_eos;
        sOut[s] = take ? idx : -1;
        if (take) {
          for (int q = 0; q < 8; ++q) if (sTaken[q] == -1) { sTaken[q] = idx; break; }
        }
        sActive = active && !is_eos;
        selSh = idx;
        if (s == NSTEPS - 1 && bid == 0) {
          for (int q = 0; q < NSTEPS; ++q) P.out[q] = (float)sOut[q];
          P.out[NSTEPS] = sTlp;
        }
      }
      __syncthreads();
    }
    if (s == NSTEPS - 1) break;   // final LSTM steps are dead code in the reference

    // ---- D: LSTM layer 0, x read directly from the selected row ----
    {
      int idx = selSh;
      const float* xrow = (idx < P.ncards) ? (P.cards + (size_t)idx * ENC) : P.eos;
      lstm_phase(P.w_ih_0, P.w_hh_0, P.b_ih_0, P.b_hh_0, xrow, h0c, c0c, h0n, c0n, sG, bid, tid);
    }
    gsync(P.bar, bid, ++ph);
    // ---- E: LSTM layer 1 ----
    lstm_phase(P.w_ih_1, P.w_hh_1, P.b_ih_1, P.b_hh_1, h0n, h1c, c1c, h1n, c1n, sG, bid, tid);
    gsync(P.bar, bid, ++ph);

    float* tp;
    tp = h0c; h0c = h0n; h0n = tp;
    tp = c0c; c0c = c0n; c0n = tp;
    tp = h1c; h1c = h1n; h1n = tp;
    tp = c1c; c1c = c1n; c1n = tp;

    // ---- A: proj for next step ----
    if (gw < ENC) {
      float acc = wred(dot8((const float4*)(P.out_w + (size_t)gw * ENC), (const float4*)h1c, lane));
      if (lane == 0) P.proj[gw] = acc + P.out_b[gw];
    }
    gsync(P.bar, bid, ++ph);
  }
}

// ================= fallback path (round-1 kernels, + gumbel table) =================
__global__ void init_kernel(float* __restrict__ Z, SelState* st) {
  int t = threadIdx.x;
  if (t < ENC) Z[t] = 0.0f;
  if (t == 0) {
    for (int i = 0; i < 8; ++i) { st->taken[i] = -1; st->outIdx[i] = -1; }
    st->takenCount = 0; st->active = 1; st->tlp = 0.0f;
  }
}

__global__ void gumbel_fill(float* __restrict__ gtab, int ncards,
                            uint32_t k00, uint32_t k01, uint32_t k10, uint32_t k11,
                            uint32_t k20, uint32_t k21, uint32_t k30, uint32_t k31,
                            uint32_t k40, uint32_t k41) {
  uint32_t K0[NSTEPS] = {k00, k10, k20, k30, k40};
  uint32_t K1[NSTEPS] = {k01, k11, k21, k31, k41};
  int np1 = ncards + 1;
  int total = NSTEPS * np1;
  for (int j = blockIdx.x * blockDim.x + threadIdx.x; j < total; j += gridDim.x * blockDim.x) {
    int s = j / np1;
    int i = j - s * np1;
    uint32_t r0, r1;
    tf2x32(K0[s], K1[s], 0u, (uint32_t)i, r0, r1);
    gtab[s * GSTRIDE + i] = gumbel_from_bits(r0 ^ r1);
  }
}

__global__ void matvec512(const float* __restrict__ W, const float* __restrict__ b,
                          const float* __restrict__ vin, float* __restrict__ vout) {
  int tid = blockIdx.x * blockDim.x + threadIdx.x;
  int wave = tid >> 6, lane = tid & 63;
  if (wave >= ENC) return;
  float acc = wred(dot8((const float4*)(W + (size_t)wave * ENC), (const float4*)vin, lane));
  if (lane == 0) vout[wave] = acc + b[wave];
}

__global__ void lstm_step_kernel(const float* __restrict__ w_ih, const float* __restrict__ w_hh,
                                 const float* __restrict__ b_ih, const float* __restrict__ b_hh,
                                 const float* __restrict__ x, const float* __restrict__ h_in,
                                 const float* __restrict__ c_in,
                                 float* __restrict__ h_out, float* __restrict__ c_out) {
  __shared__ float sG[4];
  lstm_phase(w_ih, w_hh, b_ih, b_hh, x, h_in, c_in, h_out, c_out, sG,
             blockIdx.x, threadIdx.x);
}

__global__ void sims_kernel(const float* __restrict__ cards, const float* __restrict__ eos,
                            const float* __restrict__ proj, int ncards,
                            const float* __restrict__ gt,
                            const int* __restrict__ takenList,
                            float* __restrict__ oScore, int* __restrict__ oIdx,
                            float* __restrict__ oLogit, float* __restrict__ oM,
                            float* __restrict__ oS) {
  int tid = blockIdx.x * blockDim.x + threadIdx.x;
  int wave = tid >> 6, lane = tid & 63;
  int nwav = (gridDim.x * blockDim.x) >> 6;
  const float4* pv = (const float4*)proj;
  float4 p0 = pv[lane * 2], p1 = pv[lane * 2 + 1];
  int t0 = takenList[0], t1 = takenList[1], t2 = takenList[2],
      t3 = takenList[3], t4 = takenList[4];
  float bS = -INFINITY, bL = 0.0f, m = -INFINITY, s = 0.0f;
  int bI = 0x7FFFFFFF;
  for (int i = wave; i <= ncards; i += nwav) {
    const float* rowp = (i < ncards) ? (cards + (size_t)i * ENC) : eos;
    const float4* er = (const float4*)rowp;
    float4 e0 = er[lane * 2], e1 = er[lane * 2 + 1];
    float acc = p0.x * e0.x + p0.y * e0.y + p0.z * e0.z + p0.w * e0.w +
                p1.x * e1.x + p1.y * e1.y + p1.z * e1.z + p1.w * e1.w;
    acc = wred(acc);
    bool masked = (i < ncards) &&
                  (i == t0 || i == t1 || i == t2 || i == t3 || i == t4);
    if (!masked) {
      if (acc > m) { s = s * expf(m - acc) + 1.0f; m = acc; }
      else         { s += expf(acc - m); }
      float score = gt[i] + acc;
      if (score > bS || (score == bS && i < bI)) { bS = score; bI = i; bL = acc; }
    }
  }
  if (lane == 0) { oScore[wave] = bS; oIdx[wave] = bI; oLogit[wave] = bL; oM[wave] = m; oS[wave] = s; }
}

__global__ void finalize_kernel(int nw, int step, int ncards,
                                const float* __restrict__ pScore, const int* __restrict__ pIdx,
                                const float* __restrict__ pLogit, const float* __restrict__ pM,
                                const float* __restrict__ pS,
                                const float* __restrict__ cards, const float* __restrict__ eos,
                                SelState* st, float* __restrict__ xout,
                                float* __restrict__ out, int write_out) {
  __shared__ float sS[256], sL[256], sM[256], sU[256];
  __shared__ int sI[256];
  __shared__ int selIdx;
  int t = threadIdx.x;
  float bS = -INFINITY, bL = 0.0f, m = -INFINITY, s = 0.0f;
  int bI = 0x7FFFFFFF;
  for (int i = t; i < nw; i += 256) {
    float cs = pScore[i]; int ci = pIdx[i];
    if (cs > bS || (cs == bS && ci < bI)) { bS = cs; bI = ci; bL = pLogit[i]; }
    float cm = pM[i], cu = pS[i];
    if (cm > m) { s = s * expf(m - cm) + cu; m = cm; }
    else if (cm > -INFINITY) { s += cu * expf(cm - m); }
  }
  sS[t] = bS; sI[t] = bI; sL[t] = bL; sM[t] = m; sU[t] = s;
  __syncthreads();
  for (int off = 128; off > 0; off >>= 1) {
    if (t < off) {
      float cs = sS[t + off]; int ci = sI[t + off];
      if (cs > sS[t] || (cs == sS[t] && ci < sI[t])) { sS[t] = cs; sI[t] = ci; sL[t] = sL[t + off]; }
      float cm = sM[t + off], cu = sU[t + off];
      if (cm > sM[t]) { sU[t] = sU[t] * expf(sM[t] - cm) + cu; sM[t] = cm; }
      else if (cm > -INFINITY) { sU[t] += cu * expf(cm - sM[t]); }
    }
    __syncthreads();
  }
  if (t == 0) {
    int idx = sI[0];
    float lse = sM[0] + logf(sU[0]);
    float lp = sL[0] - lse;
    int active = st->active;
    if (active) st->tlp += lp;
    int is_eos = (idx == ncards);
    int take = active && !is_eos;
    st->outIdx[step] = take ? idx : -1;
    if (take) st->taken[st->takenCount++] = idx;
    st->active = active && !is_eos;
    selIdx = idx;
    if (write_out) {
      for (int q = 0; q < NSTEPS; ++q) out[q] = (float)st->outIdx[q];
      out[NSTEPS] = st->tlp;
    }
  }
  __syncthreads();
  if (!write_out) {
    int idx = selIdx;
    const float* row = (idx < ncards) ? (cards + (size_t)idx * ENC) : eos;
    for (int e = t; e < ENC; e += 256) xout[e] = row[e];
  }
}

// ---------------- host ----------------
extern "C" void kernel_launch(void* const* d_in, const int* in_sizes, int n_in,
                              void* d_out, int out_size, void* d_ws, size_t ws_size,
                              hipStream_t stream) {
  KParams P;
  P.ctx    = (const float*)d_in[0];
  P.cards  = (const float*)d_in[1];
  P.eos    = (const float*)d_in[2];
  P.ctx_w  = (const float*)d_in[3];
  P.ctx_b  = (const float*)d_in[4];
  P.out_w  = (const float*)d_in[5];
  P.out_b  = (const float*)d_in[6];
  P.w_ih_0 = (const float*)d_in[7];
  P.w_hh_0 = (const float*)d_in[8];
  P.b_ih_0 = (const float*)d_in[9];
  P.b_hh_0 = (const float*)d_in[10];
  P.w_ih_1 = (const float*)d_in[11];
  P.w_hh_1 = (const float*)d_in[12];
  P.b_ih_1 = (const float*)d_in[13];
  P.b_hh_1 = (const float*)d_in[14];
  P.ncards = in_sizes[1] / ENC;

  char* wsb = (char*)d_ws;
  P.bar = (unsigned*)wsb;                       // 40 KB barrier region (slots + rel)
  float* f = (float*)(wsb + 40960);
  float* Z = f; f += ENC;                       // zeros (fallback)
  P.xbuf = f; f += ENC;
  P.proj = f; f += ENC;
  P.h0A = f; f += ENC;  P.c0A = f; f += ENC;
  P.h1A = f; f += ENC;  P.c1A = f; f += ENC;
  P.h0B = f; f += ENC;  P.c0B = f; f += ENC;
  P.h1B = f; f += ENC;  P.c1B = f; f += ENC;
  P.st = (SelState*)f;  f = (float*)((char*)f + 256);
  P.bScore = f; f += FB_WAVES;                  // sized for fallback (4096); coop uses [0,512)
  P.bIdxA = (int*)f; f += FB_WAVES;
  P.bLogit = f; f += FB_WAVES;
  P.bM = f; f += FB_WAVES;
  P.bS = f; f += FB_WAVES;
  P.gtab = f;
  P.out = (float*)d_out;

  for (int s = 0; s < NSTEPS; ++s)
    tf2x32(0u, 42u, 0u, (uint32_t)s, P.k0[s], P.k1[s]);

  hipMemsetAsync(P.bar, 0, 40960, stream);

  void* args[] = { &P };
  hipError_t ce = hipLaunchCooperativeKernel((void*)mega, dim3(NBLK), dim3(NTHR), args, 0, stream);
  if (ce == hipSuccess) return;
  (void)hipGetLastError();   // clear sticky error; take the classic path

  // ---------------- fallback: round-1 multi-kernel sequence ----------------
  init_kernel<<<1, 512, 0, stream>>>(Z, P.st);
  gumbel_fill<<<512, 256, 0, stream>>>(P.gtab, P.ncards,
                                       P.k0[0], P.k1[0], P.k0[1], P.k1[1], P.k0[2], P.k1[2],
                                       P.k0[3], P.k1[3], P.k0[4], P.k1[4]);
  matvec512<<<128, 256, 0, stream>>>(P.ctx_w, P.ctx_b, P.ctx, P.xbuf);
  lstm_step_kernel<<<512, 256, 0, stream>>>(P.w_ih_0, P.w_hh_0, P.b_ih_0, P.b_hh_0,
                                            P.xbuf, Z, Z, P.h0A, P.c0A);
  lstm_step_kernel<<<512, 256, 0, stream>>>(P.w_ih_1, P.w_hh_1, P.b_ih_1, P.b_hh_1,
                                            P.h0A, Z, Z, P.h1A, P.c1A);
  float *h0c = P.h0A, *c0c = P.c0A, *h1c = P.h1A, *c1c = P.c1A;
  float *h0n = P.h0B, *c0n = P.c0B, *h1n = P.h1B, *c1n = P.c1B;
  for (int s = 0; s < NSTEPS; ++s) {
    matvec512<<<128, 256, 0, stream>>>(P.out_w, P.out_b, h1c, P.proj);
    sims_kernel<<<FB_BLOCKS, 256, 0, stream>>>(P.cards, P.eos, P.proj, P.ncards,
                                               P.gtab + s * GSTRIDE, (const int*)P.st,
                                               P.bScore, P.bIdxA, P.bLogit, P.bM, P.bS);
    finalize_kernel<<<1, 256, 0, stream>>>(FB_WAVES, s, P.ncards,
                                           P.bScore, P.bIdxA, P.bLogit, P.bM, P.bS,
                                           P.cards, P.eos, P.st, P.xbuf,
                                           P.out, (s == NSTEPS - 1) ? 1 : 0);
    if (s == NSTEPS - 1) break;
    lstm_step_kernel<<<512, 256, 0, stream>>>(P.w_ih_0, P.w_hh_0, P.b_ih_0, P.b_hh_0,
                                              P.xbuf, h0c, c0c, h0n, c0n);
    lstm_step_kernel<<<512, 256, 0, stream>>>(P.w_ih_1, P.w_hh_1, P.b_ih_1, P.b_hh_1,
                                              h0n, h1c, c1c, h1n, c1n);
    float* tp;
    tp = h0c; h0c = h0n; h0n = tp;
    tp = c0c; c0c = c0n; c0n = tp;
    tp = h1c; h1c = h1n; h1n = tp;
    tp = c1c; c1c = c1n; c1n = tp;
  }
}

// Round 6
// 284.541 us; speedup vs baseline: 5.2991x; 1.8629x over previous
//
#include <hip/hip_runtime.h>
#include <stdint.h>
#include <math.h>

#define ENC 512
#define NSTEPS 5
// cooperative mega-kernel config
#define NBLK 512
#define NTHR 256
#define NWAVES ((NBLK * NTHR) / 64)       // 2048
#define ROWS_PER_ITER (NWAVES * 4)        // 8192 (4 rows per wave per iter)
// fallback sims config
#define FB_BLOCKS 1024
#define FB_WAVES (FB_BLOCKS * 256 / 64)   // 4096
#define GSTRIDE 100032                    // padded (ncards+1) stride for gumbel table

struct SelState {
  int   taken[8];
  int   takenCount;
  int   active;
  int   outIdx[8];
  float tlp;
};

struct KParams {
  const float *ctx, *cards, *eos, *ctx_w, *ctx_b, *out_w, *out_b;
  const float *w_ih_0, *w_hh_0, *b_ih_0, *b_hh_0;
  const float *w_ih_1, *w_hh_1, *b_ih_1, *b_hh_1;
  unsigned* bar;
  float* xbuf;
  float* h0s; float* c0s; float* h1s; float* c1s;   // 6 stages x 512 each
  float* projs;                                      // 5 steps x 512
  SelState* st;                                      // fallback only
  float* bScore; int* bIdxA; float* bLogit; float* bM; float* bS;  // coop: s*NBLK+bid
  float* gtab;
  float* out;
  int ncards;
  uint32_t k0[NSTEPS], k1[NSTEPS];
};

// ---------------- Threefry-2x32-20 (exact JAX implementation) ----------------
__host__ __device__ __forceinline__ void tf2x32(uint32_t k0, uint32_t k1,
                                                uint32_t x0, uint32_t x1,
                                                uint32_t& o0, uint32_t& o1) {
  uint32_t ks0 = k0, ks1 = k1, ks2 = k0 ^ k1 ^ 0x1BD11BDAu;
  uint32_t ks[3] = {ks0, ks1, ks2};
  const uint32_t R0[4] = {13u, 15u, 26u, 6u};
  const uint32_t R1[4] = {17u, 29u, 16u, 24u};
  x0 += ks0; x1 += ks1;
#pragma unroll
  for (int i = 0; i < 5; ++i) {
    const uint32_t* r = (i & 1) ? R1 : R0;
#pragma unroll
    for (int j = 0; j < 4; ++j) {
      x0 += x1;
      x1 = (x1 << r[j]) | (x1 >> (32u - r[j]));
      x1 ^= x0;
    }
    x0 += ks[(i + 1) % 3];
    x1 += ks[(i + 2) % 3] + (uint32_t)(i + 1);
  }
  o0 = x0; o1 = x1;
}

__device__ __forceinline__ float gumbel_from_bits(uint32_t bits) {
  float f = __uint_as_float((bits >> 9) | 0x3F800000u) - 1.0f;   // [0,1)
  float u = (f == 0.0f) ? 1.17549435e-38f : f;                   // minval=FLT_MIN
  return -logf(-logf(u));
}

// ---------------- XLA-matching activations ----------------
__device__ __forceinline__ float xla_tanh(float x) {
  if (fabsf(x) < 0.0004f) return x;
  const float kLim = 7.90531110763549805f;
  float cx = fminf(fmaxf(x, -kLim), kLim);
  float x2 = cx * cx;
  float p = -2.76076847742355e-16f;
  p = fmaf(p, x2, 2.00018790482477e-13f);
  p = fmaf(p, x2, -8.60467152213735e-11f);
  p = fmaf(p, x2, 5.12229709037114e-08f);
  p = fmaf(p, x2, 1.48572235717979e-05f);
  p = fmaf(p, x2, 6.37261928875436e-04f);
  p = fmaf(p, x2, 4.89352455891786e-03f);
  p = cx * p;
  float q = 1.19825839466702e-06f;
  q = fmaf(q, x2, 1.18534705686654e-04f);
  q = fmaf(q, x2, 2.26843463243900e-03f);
  q = fmaf(q, x2, 4.89352518554385e-03f);
  return p / q;
}
__device__ __forceinline__ float xla_sigmoid(float x) {
  return 0.5f * xla_tanh(0.5f * x) + 0.5f;
}

// ---------------- helpers ----------------
__device__ __forceinline__ float dot8(const float4* a, const float4* b, int lane) {
  float4 x0 = a[lane * 2], x1 = a[lane * 2 + 1];
  float4 y0 = b[lane * 2], y1 = b[lane * 2 + 1];
  return x0.x * y0.x + x0.y * y0.y + x0.z * y0.z + x0.w * y0.w +
         x1.x * y1.x + x1.y * y1.y + x1.z * y1.z + x1.w * y1.w;
}
__device__ __forceinline__ float wred(float v) {
#pragma unroll
  for (int k = 1; k < 64; k <<= 1) v += __shfl_xor(v, k, 64);
  return v;
}

// Coherence-point stores (relaxed, agent scope): bypass L2, leave no dirty
// lines, individually visible to all XCDs. NO fences => no L2 wb/inv.
__device__ __forceinline__ void cstoref(float* p, float v) {
  __hip_atomic_store(p, v, __ATOMIC_RELAXED, __HIP_MEMORY_SCOPE_AGENT);
}
__device__ __forceinline__ void cstorei(int* p, int v) {
  __hip_atomic_store(p, v, __ATOMIC_RELAXED, __HIP_MEMORY_SCOPE_AGENT);
}

// ---- fence-free grid barrier (write-once data discipline makes this legal) ----
// slots[b] at bar + b*16 (64B stride, 512 slots); rel[g] at bar + 8192 + g*16.
// Entry: per-wave s_waitcnt vmcnt(0) guarantees this block's coherence-point
// stores are globally visible (atomic-store acks come from the coherence point).
// All flag ops are RELAXED => compiler emits no buffer_wbl2 / buffer_inv.
__device__ __forceinline__ void gsync(unsigned* bar, int bid, unsigned target) {
  asm volatile("s_waitcnt vmcnt(0)" ::: "memory");
  __syncthreads();
  const int tid = threadIdx.x;
  unsigned* slots = bar;
  unsigned* rel   = bar + 8192;
  if (tid == 0)
    __hip_atomic_store(&slots[(unsigned)bid * 16u], target,
                       __ATOMIC_RELAXED, __HIP_MEMORY_SCOPE_AGENT);
  if (bid == 0) {
    unsigned* s0 = &slots[(2u * (unsigned)tid) * 16u];
    unsigned* s1 = &slots[(2u * (unsigned)tid + 1u) * 16u];
    while (__hip_atomic_load(s0, __ATOMIC_RELAXED, __HIP_MEMORY_SCOPE_AGENT) < target)
      __builtin_amdgcn_s_sleep(1);
    while (__hip_atomic_load(s1, __ATOMIC_RELAXED, __HIP_MEMORY_SCOPE_AGENT) < target)
      __builtin_amdgcn_s_sleep(1);
    __syncthreads();                     // all 512 arrivals observed (+compiler barrier)
    if (tid < 64)
      __hip_atomic_store(&rel[(unsigned)tid * 16u], target,
                         __ATOMIC_RELAXED, __HIP_MEMORY_SCOPE_AGENT);
  } else {
    if (tid == 0) {
      unsigned* r = &rel[((unsigned)bid & 63u) * 16u];
      while (__hip_atomic_load(r, __ATOMIC_RELAXED, __HIP_MEMORY_SCOPE_AGENT) < target)
        __builtin_amdgcn_s_sleep(1);
    }
    __syncthreads();                     // compiler barrier: no load hoisting above poll
  }
}

// ---------------- LSTM phase: blocks 0..511, block = output column ----------------
// h/c outputs go through cstore (write-once per-step buffers).
__device__ __forceinline__ void lstm_phase(const float* wih, const float* whh,
                                           const float* bih, const float* bhh,
                                           const float* x, const float* hin, const float* cin,
                                           float* hout, float* cout, float* sG,
                                           int bid, int tid) {
  if (bid < ENC) {
    int g = tid >> 6, lane = tid & 63;
    size_t row = (size_t)(g * ENC + bid) * ENC;
    float accI = dot8((const float4*)(wih + row), (const float4*)x, lane);
    float accH = 0.0f;
    if (hin) accH = dot8((const float4*)(whh + row), (const float4*)hin, lane);
#pragma unroll
    for (int k = 1; k < 64; k <<= 1) {
      accI += __shfl_xor(accI, k, 64);
      accH += __shfl_xor(accH, k, 64);
    }
    if (lane == 0) sG[g] = ((accI + bih[g * ENC + bid]) + accH) + bhh[g * ENC + bid];
    __syncthreads();
    if (tid == 0) {
      float gi = sG[0], gf = sG[1], gg = sG[2], go = sG[3];
      float cprev = cin ? cin[bid] : 0.0f;
      float cn = xla_sigmoid(gf) * cprev + xla_sigmoid(gi) * xla_tanh(gg);
      float hn = xla_sigmoid(go) * xla_tanh(cn);
      cstoref(&cout[bid], cn);
      cstoref(&hout[bid], hn);
    }
  }
}

// ---------------- the cooperative mega kernel ----------------
__global__ __launch_bounds__(NTHR, 2) void mega(KParams P) {
  const int bid = blockIdx.x, tid = threadIdx.x;
  const int wid = tid >> 6, lane = tid & 63;
  const int gw = bid * 4 + wid;
  const int sub = lane & 15;    // position within 16-lane row group
  const int grp = lane >> 4;    // row group 0..3
  unsigned ph = 0;

  __shared__ float sG[4];
  __shared__ float fS[NTHR], fL[NTHR], fM[NTHR], fU[NTHR];
  __shared__ int   fI[NTHR];
  __shared__ float wSs[16], wLs[16], wMs[16], wUs[16];
  __shared__ int   wIs[16];
  __shared__ int   sTaken[8];
  __shared__ int   sActive;
  __shared__ float sTlp;
  __shared__ int   sOut[NSTEPS];
  __shared__ int   selSh;

  if (tid == 0) {
    for (int i = 0; i < 8; ++i) sTaken[i] = -1;
    sActive = 1; sTlp = 0.0f;
    for (int i = 0; i < NSTEPS; ++i) sOut[i] = -1;
  }

  const int np1 = P.ncards + 1;
  const int ITERS = (np1 + ROWS_PER_ITER - 1) / ROWS_PER_ITER;

  // ---- phase 0: gumbel table + x0 = ctx @ ctx_w.T + ctx_b ----
  {
    int total = NSTEPS * np1;
    for (int j = bid * NTHR + tid; j < total; j += NBLK * NTHR) {
      int s = j / np1;
      int i = j - s * np1;
      uint32_t r0, r1;
      tf2x32(P.k0[s], P.k1[s], 0u, (uint32_t)i, r0, r1);
      cstoref(&P.gtab[s * GSTRIDE + i], gumbel_from_bits(r0 ^ r1));
    }
  }
  if (gw >= NWAVES - ENC) {
    int r = gw - (NWAVES - ENC);
    float acc = wred(dot8((const float4*)(P.ctx_w + (size_t)r * ENC), (const float4*)P.ctx, lane));
    if (lane == 0) cstoref(&P.xbuf[r], acc + P.ctx_b[r]);
  }
  gsync(P.bar, bid, ++ph);

  // ---- initial LSTM steps (zero state) -> stage 0 ----
  lstm_phase(P.w_ih_0, P.w_hh_0, P.b_ih_0, P.b_hh_0, P.xbuf, nullptr, nullptr,
             P.h0s, P.c0s, sG, bid, tid);
  gsync(P.bar, bid, ++ph);
  lstm_phase(P.w_ih_1, P.w_hh_1, P.b_ih_1, P.b_hh_1, P.h0s, nullptr, nullptr,
             P.h1s, P.c1s, sG, bid, tid);
  gsync(P.bar, bid, ++ph);

  // ---- proj for step 0 ----
  if (gw < ENC) {
    float acc = wred(dot8((const float4*)(P.out_w + (size_t)gw * ENC), (const float4*)P.h1s, lane));
    if (lane == 0) cstoref(&P.projs[gw], acc + P.out_b[gw]);
  }
  gsync(P.bar, bid, ++ph);

  for (int s = 0; s < NSTEPS; ++s) {
    // ---- B: sims, 16-lane row groups (4 rows/wave/iter), proj in registers ----
    {
      const float4* pv = (const float4*)(P.projs + s * ENC);
      float4 pr[8];
#pragma unroll
      for (int k = 0; k < 8; ++k) pr[k] = pv[sub + 16 * k];
      int t0 = sTaken[0], t1 = sTaken[1], t2 = sTaken[2], t3 = sTaken[3], t4 = sTaken[4];
      const float* gt = P.gtab + s * GSTRIDE;
      float bSc = -INFINITY, bLg = 0.0f, m = -INFINITY, su = 0.0f;
      int bIx = 0x7FFFFFFF;
      for (int t = 0; t < ITERS; ++t) {
        int r = (t * NWAVES + gw) * 4 + grp;
        bool valid = (r < np1);
        const float* rowp = valid ? ((r < P.ncards) ? (P.cards + (size_t)r * ENC) : P.eos)
                                  : P.cards;
        const float4* rv = (const float4*)rowp;
        float4 rr[8];
#pragma unroll
        for (int k = 0; k < 8; ++k) rr[k] = rv[sub + 16 * k];
        float acc = 0.0f;
#pragma unroll
        for (int k = 0; k < 8; ++k)
          acc += rr[k].x * pr[k].x + rr[k].y * pr[k].y + rr[k].z * pr[k].z + rr[k].w * pr[k].w;
        acc += __shfl_xor(acc, 1, 64);
        acc += __shfl_xor(acc, 2, 64);
        acc += __shfl_xor(acc, 4, 64);
        acc += __shfl_xor(acc, 8, 64);
        if (valid && sub == 0) {
          bool masked = (r < P.ncards) &&
                        (r == t0 || r == t1 || r == t2 || r == t3 || r == t4);
          if (!masked) {
            if (acc > m) { su = su * expf(m - acc) + 1.0f; m = acc; }
            else         { su += expf(acc - m); }
            float score = gt[r] + acc;
            if (score > bSc || (score == bSc && r < bIx)) { bSc = score; bIx = r; bLg = acc; }
          }
        }
      }
      if (sub == 0) {
        int q = wid * 4 + grp;
        wSs[q] = bSc; wIs[q] = bIx; wLs[q] = bLg; wMs[q] = m; wUs[q] = su;
      }
      __syncthreads();
      if (tid == 0) {
        float s2 = wSs[0], l2 = wLs[0], m2 = wMs[0], u2 = wUs[0];
        int i2 = wIs[0];
        for (int k = 1; k < 16; ++k) {
          float cs = wSs[k]; int ci = wIs[k];
          if (cs > s2 || (cs == s2 && ci < i2)) { s2 = cs; i2 = ci; l2 = wLs[k]; }
          float cm = wMs[k], cu = wUs[k];
          if (cm > m2) { u2 = u2 * expf(m2 - cm) + cu; m2 = cm; }
          else if (cm > -INFINITY) { u2 += cu * expf(cm - m2); }
        }
        int o = s * NBLK + bid;
        cstoref(&P.bScore[o], s2); cstorei(&P.bIdxA[o], i2);
        cstoref(&P.bLogit[o], l2); cstoref(&P.bM[o], m2); cstoref(&P.bS[o], u2);
      }
    }
    gsync(P.bar, bid, ++ph);

    // ---- C': every block reduces the 512 partials (identical result) ----
    {
      const float* pSc = P.bScore + s * NBLK;
      const int*   pIx = P.bIdxA  + s * NBLK;
      const float* pLg = P.bLogit + s * NBLK;
      const float* pMm = P.bM     + s * NBLK;
      const float* pSu = P.bS     + s * NBLK;
      float bS2 = -INFINITY, bL2 = 0.0f, m = -INFINITY, su = 0.0f;
      int bI2 = 0x7FFFFFFF;
      for (int i = tid; i < NBLK; i += NTHR) {
        float cs = pSc[i]; int ci = pIx[i];
        if (cs > bS2 || (cs == bS2 && ci < bI2)) { bS2 = cs; bI2 = ci; bL2 = pLg[i]; }
        float cm = pMm[i], cu = pSu[i];
        if (cm > m) { su = su * expf(m - cm) + cu; m = cm; }
        else if (cm > -INFINITY) { su += cu * expf(cm - m); }
      }
      fS[tid] = bS2; fI[tid] = bI2; fL[tid] = bL2; fM[tid] = m; fU[tid] = su;
      __syncthreads();
      for (int off = 128; off > 0; off >>= 1) {
        if (tid < off) {
          float cs = fS[tid + off]; int ci = fI[tid + off];
          if (cs > fS[tid] || (cs == fS[tid] && ci < fI[tid])) {
            fS[tid] = cs; fI[tid] = ci; fL[tid] = fL[tid + off];
          }
          float cm = fM[tid + off], cu = fU[tid + off];
          if (cm > fM[tid]) { fU[tid] = fU[tid] * expf(fM[tid] - cm) + cu; fM[tid] = cm; }
          else if (cm > -INFINITY) { fU[tid] += cu * expf(cm - fM[tid]); }
        }
        __syncthreads();
      }
      if (tid == 0) {
        int idx = fI[0];
        float lse = fM[0] + logf(fU[0]);
        float lp = fL[0] - lse;
        int active = sActive;
        if (active) sTlp += lp;
        int is_eos = (idx == P.ncards);
        int take = active && !is_eos;
        sOut[s] = take ? idx : -1;
        if (take) {
          for (int q = 0; q < 8; ++q) if (sTaken[q] == -1) { sTaken[q] = idx; break; }
        }
        sActive = active && !is_eos;
        selSh = idx;
        if (s == NSTEPS - 1 && bid == 0) {
          for (int q = 0; q < NSTEPS; ++q) P.out[q] = (float)sOut[q];
          P.out[NSTEPS] = sTlp;
        }
      }
      __syncthreads();
    }
    if (s == NSTEPS - 1) break;   // final LSTM steps are dead code in the reference

    // ---- D: LSTM layer 0 (stage s -> s+1), x read from the selected row ----
    {
      int idx = selSh;
      const float* xrow = (idx < P.ncards) ? (P.cards + (size_t)idx * ENC) : P.eos;
      lstm_phase(P.w_ih_0, P.w_hh_0, P.b_ih_0, P.b_hh_0, xrow,
                 P.h0s + s * ENC, P.c0s + s * ENC,
                 P.h0s + (s + 1) * ENC, P.c0s + (s + 1) * ENC, sG, bid, tid);
    }
    gsync(P.bar, bid, ++ph);
    // ---- E: LSTM layer 1 ----
    lstm_phase(P.w_ih_1, P.w_hh_1, P.b_ih_1, P.b_hh_1, P.h0s + (s + 1) * ENC,
               P.h1s + s * ENC, P.c1s + s * ENC,
               P.h1s + (s + 1) * ENC, P.c1s + (s + 1) * ENC, sG, bid, tid);
    gsync(P.bar, bid, ++ph);

    // ---- A: proj for next step ----
    if (gw < ENC) {
      float acc = wred(dot8((const float4*)(P.out_w + (size_t)gw * ENC),
                            (const float4*)(P.h1s + (s + 1) * ENC), lane));
      if (lane == 0) cstoref(&P.projs[(s + 1) * ENC + gw], acc + P.out_b[gw]);
    }
    gsync(P.bar, bid, ++ph);
  }
}

// ================= fallback path (round-1 kernels, + gumbel table) =================
__global__ void init_kernel(float* __restrict__ Z, SelState* st) {
  int t = threadIdx.x;
  if (t < ENC) Z[t] = 0.0f;
  if (t == 0) {
    for (int i = 0; i < 8; ++i) { st->taken[i] = -1; st->outIdx[i] = -1; }
    st->takenCount = 0; st->active = 1; st->tlp = 0.0f;
  }
}

__global__ void gumbel_fill(float* __restrict__ gtab, int ncards,
                            uint32_t k00, uint32_t k01, uint32_t k10, uint32_t k11,
                            uint32_t k20, uint32_t k21, uint32_t k30, uint32_t k31,
                            uint32_t k40, uint32_t k41) {
  uint32_t K0[NSTEPS] = {k00, k10, k20, k30, k40};
  uint32_t K1[NSTEPS] = {k01, k11, k21, k31, k41};
  int np1 = ncards + 1;
  int total = NSTEPS * np1;
  for (int j = blockIdx.x * blockDim.x + threadIdx.x; j < total; j += gridDim.x * blockDim.x) {
    int s = j / np1;
    int i = j - s * np1;
    uint32_t r0, r1;
    tf2x32(K0[s], K1[s], 0u, (uint32_t)i, r0, r1);
    gtab[s * GSTRIDE + i] = gumbel_from_bits(r0 ^ r1);
  }
}

__global__ void matvec512(const float* __restrict__ W, const float* __restrict__ b,
                          const float* __restrict__ vin, float* __restrict__ vout) {
  int tid = blockIdx.x * blockDim.x + threadIdx.x;
  int wave = tid >> 6, lane = tid & 63;
  if (wave >= ENC) return;
  float acc = wred(dot8((const float4*)(W + (size_t)wave * ENC), (const float4*)vin, lane));
  if (lane == 0) vout[wave] = acc + b[wave];
}

__global__ void lstm_step_kernel(const float* __restrict__ w_ih, const float* __restrict__ w_hh,
                                 const float* __restrict__ b_ih, const float* __restrict__ b_hh,
                                 const float* __restrict__ x, const float* __restrict__ h_in,
                                 const float* __restrict__ c_in,
                                 float* __restrict__ h_out, float* __restrict__ c_out) {
  __shared__ float sG[4];
  // fallback runs as separate kernels; cstore in lstm_phase is harmless here
  lstm_phase(w_ih, w_hh, b_ih, b_hh, x, h_in, c_in, h_out, c_out, sG,
             blockIdx.x, threadIdx.x);
}

__global__ void sims_kernel(const float* __restrict__ cards, const float* __restrict__ eos,
                            const float* __restrict__ proj, int ncards,
                            const float* __restrict__ gt,
                            const int* __restrict__ takenList,
                            float* __restrict__ oScore, int* __restrict__ oIdx,
                            float* __restrict__ oLogit, float* __restrict__ oM,
                            float* __restrict__ oS) {
  int tid = blockIdx.x * blockDim.x + threadIdx.x;
  int wave = tid >> 6, lane = tid & 63;
  int nwav = (gridDim.x * blockDim.x) >> 6;
  const float4* pv = (const float4*)proj;
  float4 p0 = pv[lane * 2], p1 = pv[lane * 2 + 1];
  int t0 = takenList[0], t1 = takenList[1], t2 = takenList[2],
      t3 = takenList[3], t4 = takenList[4];
  float bS = -INFINITY, bL = 0.0f, m = -INFINITY, s = 0.0f;
  int bI = 0x7FFFFFFF;
  for (int i = wave; i <= ncards; i += nwav) {
    const float* rowp = (i < ncards) ? (cards + (size_t)i * ENC) : eos;
    const float4* er = (const float4*)rowp;
    float4 e0 = er[lane * 2], e1 = er[lane * 2 + 1];
    float acc = p0.x * e0.x + p0.y * e0.y + p0.z * e0.z + p0.w * e0.w +
                p1.x * e1.x + p1.y * e1.y + p1.z * e1.z + p1.w * e1.w;
    acc = wred(acc);
    bool masked = (i < ncards) &&
                  (i == t0 || i == t1 || i == t2 || i == t3 || i == t4);
    if (!masked) {
      if (acc > m) { s = s * expf(m - acc) + 1.0f; m = acc; }
      else         { s += expf(acc - m); }
      float score = gt[i] + acc;
      if (score > bS || (score == bS && i < bI)) { bS = score; bI = i; bL = acc; }
    }
  }
  if (lane == 0) { oScore[wave] = bS; oIdx[wave] = bI; oLogit[wave] = bL; oM[wave] = m; oS[wave] = s; }
}

__global__ void finalize_kernel(int nw, int step, int ncards,
                                const float* __restrict__ pScore, const int* __restrict__ pIdx,
                                const float* __restrict__ pLogit, const float* __restrict__ pM,
                                const float* __restrict__ pS,
                                const float* __restrict__ cards, const float* __restrict__ eos,
                                SelState* st, float* __restrict__ xout,
                                float* __restrict__ out, int write_out) {
  __shared__ float sS[256], sL[256], sM[256], sU[256];
  __shared__ int sI[256];
  __shared__ int selIdx;
  int t = threadIdx.x;
  float bS = -INFINITY, bL = 0.0f, m = -INFINITY, s = 0.0f;
  int bI = 0x7FFFFFFF;
  for (int i = t; i < nw; i += 256) {
    float cs = pScore[i]; int ci = pIdx[i];
    if (cs > bS || (cs == bS && ci < bI)) { bS = cs; bI = ci; bL = pLogit[i]; }
    float cm = pM[i], cu = pS[i];
    if (cm > m) { s = s * expf(m - cm) + cu; m = cm; }
    else if (cm > -INFINITY) { s += cu * expf(cm - m); }
  }
  sS[t] = bS; sI[t] = bI; sL[t] = bL; sM[t] = m; sU[t] = s;
  __syncthreads();
  for (int off = 128; off > 0; off >>= 1) {
    if (t < off) {
      float cs = sS[t + off]; int ci = sI[t + off];
      if (cs > sS[t] || (cs == sS[t] && ci < sI[t])) { sS[t] = cs; sI[t] = ci; sL[t] = sL[t + off]; }
      float cm = sM[t + off], cu = sU[t + off];
      if (cm > sM[t]) { sU[t] = sU[t] * expf(sM[t] - cm) + cu; sM[t] = cm; }
      else if (cm > -INFINITY) { sU[t] += cu * expf(cm - sM[t]); }
    }
    __syncthreads();
  }
  if (t == 0) {
    int idx = sI[0];
    float lse = sM[0] + logf(sU[0]);
    float lp = sL[0] - lse;
    int active = st->active;
    if (active) st->tlp += lp;
    int is_eos = (idx == ncards);
    int take = active && !is_eos;
    st->outIdx[step] = take ? idx : -1;
    if (take) st->taken[st->takenCount++] = idx;
    st->active = active && !is_eos;
    selIdx = idx;
    if (write_out) {
      for (int q = 0; q < NSTEPS; ++q) out[q] = (float)st->outIdx[q];
      out[NSTEPS] = st->tlp;
    }
  }
  __syncthreads();
  if (!write_out) {
    int idx = selIdx;
    const float* row = (idx < ncards) ? (cards + (size_t)idx * ENC) : eos;
    for (int e = t; e < ENC; e += 256) xout[e] = row[e];
  }
}

// ---------------- host ----------------
extern "C" void kernel_launch(void* const* d_in, const int* in_sizes, int n_in,
                              void* d_out, int out_size, void* d_ws, size_t ws_size,
                              hipStream_t stream) {
  KParams P;
  P.ctx    = (const float*)d_in[0];
  P.cards  = (const float*)d_in[1];
  P.eos    = (const float*)d_in[2];
  P.ctx_w  = (const float*)d_in[3];
  P.ctx_b  = (const float*)d_in[4];
  P.out_w  = (const float*)d_in[5];
  P.out_b  = (const float*)d_in[6];
  P.w_ih_0 = (const float*)d_in[7];
  P.w_hh_0 = (const float*)d_in[8];
  P.b_ih_0 = (const float*)d_in[9];
  P.b_hh_0 = (const float*)d_in[10];
  P.w_ih_1 = (const float*)d_in[11];
  P.w_hh_1 = (const float*)d_in[12];
  P.b_ih_1 = (const float*)d_in[13];
  P.b_hh_1 = (const float*)d_in[14];
  P.ncards = in_sizes[1] / ENC;

  char* wsb = (char*)d_ws;
  P.bar = (unsigned*)wsb;                       // 40 KB barrier region (slots + rel)
  float* f = (float*)(wsb + 40960);
  float* Z = f; f += ENC;                       // zeros (fallback)
  P.xbuf = f; f += ENC;
  P.h0s = f; f += 6 * ENC;
  P.c0s = f; f += 6 * ENC;
  P.h1s = f; f += 6 * ENC;
  P.c1s = f; f += 6 * ENC;
  P.projs = f; f += NSTEPS * ENC;
  P.st = (SelState*)f;  f = (float*)((char*)f + 256);
  P.bScore = f; f += FB_WAVES;                  // coop uses [0, 5*NBLK) within these
  P.bIdxA = (int*)f; f += FB_WAVES;
  P.bLogit = f; f += FB_WAVES;
  P.bM = f; f += FB_WAVES;
  P.bS = f; f += FB_WAVES;
  P.gtab = f;
  P.out = (float*)d_out;

  for (int s = 0; s < NSTEPS; ++s)
    tf2x32(0u, 42u, 0u, (uint32_t)s, P.k0[s], P.k1[s]);

  hipMemsetAsync(P.bar, 0, 40960, stream);

  void* args[] = { &P };
  hipError_t ce = hipLaunchCooperativeKernel((void*)mega, dim3(NBLK), dim3(NTHR), args, 0, stream);
  if (ce == hipSuccess) return;
  (void)hipGetLastError();   // clear sticky error; take the classic path

  // ---------------- fallback: round-1 multi-kernel sequence ----------------
  float* h0A = P.h0s;            float* h0B = P.h0s + ENC;
  float* c0A = P.c0s;            float* c0B = P.c0s + ENC;
  float* h1A = P.h1s;            float* h1B = P.h1s + ENC;
  float* c1A = P.c1s;            float* c1B = P.c1s + ENC;
  float* proj = P.projs;
  float* xbuf = P.xbuf;

  init_kernel<<<1, 512, 0, stream>>>(Z, P.st);
  gumbel_fill<<<512, 256, 0, stream>>>(P.gtab, P.ncards,
                                       P.k0[0], P.k1[0], P.k0[1], P.k1[1], P.k0[2], P.k1[2],
                                       P.k0[3], P.k1[3], P.k0[4], P.k1[4]);
  matvec512<<<128, 256, 0, stream>>>(P.ctx_w, P.ctx_b, P.ctx, xbuf);
  lstm_step_kernel<<<512, 256, 0, stream>>>(P.w_ih_0, P.w_hh_0, P.b_ih_0, P.b_hh_0,
                                            xbuf, Z, Z, h0A, c0A);
  lstm_step_kernel<<<512, 256, 0, stream>>>(P.w_ih_1, P.w_hh_1, P.b_ih_1, P.b_hh_1,
                                            h0A, Z, Z, h1A, c1A);
  float *h0c = h0A, *c0c = c0A, *h1c = h1A, *c1c = c1A;
  float *h0n = h0B, *c0n = c0B, *h1n = h1B, *c1n = c1B;
  for (int s = 0; s < NSTEPS; ++s) {
    matvec512<<<128, 256, 0, stream>>>(P.out_w, P.out_b, h1c, proj);
    sims_kernel<<<FB_BLOCKS, 256, 0, stream>>>(P.cards, P.eos, proj, P.ncards,
                                               P.gtab + s * GSTRIDE, (const int*)P.st,
                                               P.bScore, P.bIdxA, P.bLogit, P.bM, P.bS);
    finalize_kernel<<<1, 256, 0, stream>>>(FB_WAVES, s, P.ncards,
                                           P.bScore, P.bIdxA, P.bLogit, P.bM, P.bS,
                                           P.cards, P.eos, P.st, xbuf,
                                           P.out, (s == NSTEPS - 1) ? 1 : 0);
    if (s == NSTEPS - 1) break;
    lstm_step_kernel<<<512, 256, 0, stream>>>(P.w_ih_0, P.w_hh_0, P.b_ih_0, P.b_hh_0,
                                              xbuf, h0c, c0c, h0n, c0n);
    lstm_step_kernel<<<512, 256, 0, stream>>>(P.w_ih_1, P.w_hh_1, P.b_ih_1, P.b_hh_1,
                                              h0n, h1c, c1c, h1n, c1n);
    float* tp;
    tp = h0c; h0c = h0n; h0n = tp;
    tp = c0c; c0c = c0n; c0n = tp;
    tp = h1c; h1c = h1n; h1n = tp;
    tp = c1c; c1c = c1n; c1n = tp;
  }
}